// Round 5
// baseline (818.406 us; speedup 1.0000x reference)
//
#include <hip/hip_runtime.h>
#include <hip/hip_bf16.h>
#include <cstdint>
#include <cstddef>

#define DIMC 1024
#define HEADS 16
#define HD 64
#define DFF 4096
#define BB 4
#define SS 4096
#define NROWS (BB*SS)   // 16384

typedef __bf16 bf16_t;
typedef __bf16 bf16x8 __attribute__((ext_vector_type(8)));
typedef __bf16 bf16x4 __attribute__((ext_vector_type(4)));
typedef float  f32x4  __attribute__((ext_vector_type(4)));

#define GLDS16(gp, lp) \
  __builtin_amdgcn_global_load_lds((const __attribute__((address_space(1))) void*)(gp), \
                                   (__attribute__((address_space(3))) void*)(lp), 16, 0, 0)

// ---------------------------------------------------------------- weight transpose f32[K][N] -> bf16[N][K]
__global__ __launch_bounds__(256) void wtrans(const float* __restrict__ W, bf16_t* __restrict__ Wt,
                                              int K, int N) {
  __shared__ float tile[32][33];
  int c0 = blockIdx.x * 32, r0 = blockIdx.y * 32;
  int tx = threadIdx.x, ty = threadIdx.y;
  #pragma unroll
  for (int i = 0; i < 32; i += 8)
    tile[ty + i][tx] = W[(long)(r0 + ty + i) * N + c0 + tx];
  __syncthreads();
  #pragma unroll
  for (int i = 0; i < 32; i += 8)
    Wt[(long)(c0 + ty + i) * K + r0 + tx] = (bf16_t)tile[tx][ty + i];
}

// ---------------------------------------------------------------- LayerNorm f32 row -> bf16 row
__global__ __launch_bounds__(256) void ln_kernel(const float* __restrict__ in,
                                                 const float* __restrict__ gamma,
                                                 const float* __restrict__ beta,
                                                 bf16_t* __restrict__ out) {
  long r = blockIdx.x;
  int t = threadIdx.x;
  float4 v = ((const float4*)(in + r * DIMC))[t];
  float s  = v.x + v.y + v.z + v.w;
  float sq = v.x * v.x + v.y * v.y + v.z * v.z + v.w * v.w;
  #pragma unroll
  for (int o = 32; o > 0; o >>= 1) { s += __shfl_xor(s, o); sq += __shfl_xor(sq, o); }
  __shared__ float red[8];
  if ((t & 63) == 0) { red[(t >> 6) * 2] = s; red[(t >> 6) * 2 + 1] = sq; }
  __syncthreads();
  s  = red[0] + red[2] + red[4] + red[6];
  sq = red[1] + red[3] + red[5] + red[7];
  float mu  = s * (1.0f / DIMC);
  float var = sq * (1.0f / DIMC) - mu * mu;
  float rs  = 1.0f / sqrtf(var + 1e-5f);
  float4 g  = ((const float4*)gamma)[t];
  float4 bb = ((const float4*)beta)[t];
  bf16x4 o;
  o[0] = (bf16_t)((v.x - mu) * rs * g.x + bb.x);
  o[1] = (bf16_t)((v.y - mu) * rs * g.y + bb.y);
  o[2] = (bf16_t)((v.z - mu) * rs * g.z + bb.z);
  o[3] = (bf16_t)((v.w - mu) * rs * g.w + bb.w);
  ((bf16x4*)(out + r * DIMC))[t] = o;
}

// ---------------------------------------------------------------- 256x256 GEMM, 8 waves, BK=64, counted-vmcnt dbuf, XOR-swizzled LDS
// A[M][K] bf16 @ Bt[N][K] bf16.  MODE 0: bf16 = acc+bias   MODE 1: f32 = acc+bias+resid   MODE 2: bf16 = gelu(acc+bias)
template <int MODE>
__global__ __launch_bounds__(512, 2) void gemm256(const bf16_t* __restrict__ A,
                                                  const bf16_t* __restrict__ Bt,
                                                  const float* __restrict__ bias,
                                                  const float* __restrict__ resid,
                                                  void* __restrict__ outp,
                                                  int M, int N, int K) {
  // [slot][op A=0/B=1][row 0..255][col 0..63 bf16]  = 128 KiB
  __shared__ bf16_t lds[2][2][256][64];
  const int tid  = threadIdx.x;
  const int lane = tid & 63;
  const int wid  = tid >> 6;          // 0..7
  const int wr   = wid >> 2;          // 0..1  M-half of the tile
  const int wc   = wid & 3;           // 0..3  N-quarter of the tile
  const long arow0 = (long)blockIdx.y * 256;
  const long brow0 = (long)blockIdx.x * 256;

  const int srow   = tid >> 3;        // staging: row within 64-row pass
  const int schunk = tid & 7;         // staging: 16B chunk within 128B row

  const int fr = lane & 15;
  const int q4 = lane >> 4;           // 0..3

  f32x4 acc[8][4] = {};
  const int NT = K >> 6;

  // stage one K-tile (A 256x64 + B 256x64) into slot s: 8 gload_lds per wave.
  // LDS dest linear; global source pre-permuted by the same XOR the reads use (rule #21).
  auto STAGE = [&](int kt, int s) {
    const int k0 = kt << 6;
    #pragma unroll
    for (int p = 0; p < 8; ++p) {
      const int op = p >> 2, pass = p & 3;
      const int row = pass * 64 + srow;
      const long grow = (op ? brow0 : arow0) + row;
      const int gch = schunk ^ (row & 7);
      const bf16_t* src = (op ? Bt : A) + grow * (long)K + k0 + gch * 8;
      GLDS16(src, &lds[s][op][row][schunk * 8]);
    }
  };

  auto COMPUTE = [&](int s) {
    bf16x8 bfrag[4][2];
    #pragma unroll
    for (int j = 0; j < 4; ++j) {
      const int row = wc * 64 + j * 16 + fr;
      bfrag[j][0] = *(const bf16x8*)&lds[s][1][row][((q4    ) ^ (row & 7)) * 8];
      bfrag[j][1] = *(const bf16x8*)&lds[s][1][row][((q4 + 4) ^ (row & 7)) * 8];
    }
    __builtin_amdgcn_s_setprio(1);
    #pragma unroll
    for (int i = 0; i < 8; ++i) {
      const int row = wr * 128 + i * 16 + fr;
      bf16x8 a0 = *(const bf16x8*)&lds[s][0][row][((q4    ) ^ (row & 7)) * 8];
      bf16x8 a1 = *(const bf16x8*)&lds[s][0][row][((q4 + 4) ^ (row & 7)) * 8];
      #pragma unroll
      for (int j = 0; j < 4; ++j) {
        acc[i][j] = __builtin_amdgcn_mfma_f32_16x16x32_bf16(a0, bfrag[j][0], acc[i][j], 0, 0, 0);
        acc[i][j] = __builtin_amdgcn_mfma_f32_16x16x32_bf16(a1, bfrag[j][1], acc[i][j], 0, 0, 0);
      }
    }
    __builtin_amdgcn_s_setprio(0);
  };

  STAGE(0, 0);
  if (NT > 1) STAGE(1, 1);

  for (int t = 0; t < NT; ++t) {
    const int s = t & 1;
    // counted wait: my tile-t loads (oldest 8) landed; tile-t+1's stay in flight
    if (t + 1 < NT) asm volatile("s_waitcnt vmcnt(8)" ::: "memory");
    else            asm volatile("s_waitcnt vmcnt(0)" ::: "memory");
    __builtin_amdgcn_sched_barrier(0);
    __builtin_amdgcn_s_barrier();            // everyone's tile-t data in LDS
    __builtin_amdgcn_sched_barrier(0);
    asm volatile("" ::: "memory");
    COMPUTE(s);
    asm volatile("" ::: "memory");
    __builtin_amdgcn_sched_barrier(0);
    __builtin_amdgcn_s_barrier();            // everyone done READING slot s
    __builtin_amdgcn_sched_barrier(0);
    if (t + 2 < NT) STAGE(t + 2, s);         // prefetch into freed slot
  }

  const int rq = q4 * 4;
  #pragma unroll
  for (int i = 0; i < 8; ++i) {
    #pragma unroll
    for (int j = 0; j < 4; ++j) {
      long col = brow0 + wc * 64 + j * 16 + fr;
      float bv = bias[col];
      #pragma unroll
      for (int r = 0; r < 4; ++r) {
        long row = arow0 + wr * 128 + i * 16 + rq + r;
        float v = acc[i][j][r] + bv;
        if (MODE == 0) {
          ((bf16_t*)outp)[row * N + col] = (bf16_t)v;
        } else if (MODE == 1) {
          ((float*)outp)[row * N + col] = v + resid[row * N + col];
        } else {
          float g = 0.5f * v * (1.0f + erff(v * 0.70710678118654752f));
          ((bf16_t*)outp)[row * N + col] = (bf16_t)g;
        }
      }
    }
  }
}

// ---------------------------------------------------------------- q softmax (in-place, per (row, head) over 64)
__global__ __launch_bounds__(256) void qsoftmax(bf16_t* __restrict__ qkv) {
  long r = blockIdx.x;
  int t = threadIdx.x, h = t >> 4, l = t & 15;
  bf16_t* p = qkv + r * 3072 + h * 64 + l * 4;
  bf16x4 v4 = *(const bf16x4*)p;
  float v0 = v4[0], v1 = v4[1], v2 = v4[2], v3 = v4[3];
  float m = fmaxf(fmaxf(v0, v1), fmaxf(v2, v3));
  #pragma unroll
  for (int o = 8; o >= 1; o >>= 1) m = fmaxf(m, __shfl_xor(m, o));
  float e0 = __expf(v0 - m), e1 = __expf(v1 - m), e2 = __expf(v2 - m), e3 = __expf(v3 - m);
  float s = e0 + e1 + e2 + e3;
  #pragma unroll
  for (int o = 8; o >= 1; o >>= 1) s += __shfl_xor(s, o);
  float inv = 1.0f / s;
  bf16x4 o4;
  o4[0] = (bf16_t)(e0 * inv); o4[1] = (bf16_t)(e1 * inv);
  o4[2] = (bf16_t)(e2 * inv); o4[3] = (bf16_t)(e3 * inv);
  *(bf16x4*)p = o4;
}

// ---------------------------------------------------------------- k column-softmax stats (online max/sum partials)
__global__ __launch_bounds__(256) void kstats_partial(const bf16_t* __restrict__ qkv,
                                                      float2* __restrict__ part) {
  int bh = blockIdx.x, ch = blockIdx.y;
  int b = bh >> 4, h = bh & 15;
  int t = threadIdx.x, d = t & 63, sr = t >> 6;
  const bf16_t* kp = qkv + (long)b * SS * 3072 + 1024 + h * 64 + d;
  float m = -INFINITY, sum = 0.f;
  for (int s = ch * 512 + sr; s < ch * 512 + 512; s += 4) {
    float v = (float)kp[(long)s * 3072];
    float nm = fmaxf(m, v);
    sum = sum * __expf(m - nm) + __expf(v - nm);
    m = nm;
  }
  __shared__ float2 red[4][64];
  red[sr][d] = make_float2(m, sum);
  __syncthreads();
  if (t < 64) {
    float2 a = red[0][t];
    #pragma unroll
    for (int i = 1; i < 4; ++i) {
      float2 p = red[i][t];
      float nm = fmaxf(a.x, p.x);
      a.y = a.y * __expf(a.x - nm) + p.y * __expf(p.x - nm);
      a.x = nm;
    }
    part[(long)(bh * 8 + ch) * 64 + t] = a;
  }
}

__global__ void kstats_merge(const float2* __restrict__ part, float2* __restrict__ stat) {
  int bh = blockIdx.x, d = threadIdx.x;  // 64 threads
  float m = -INFINITY, s = 0.f;
  #pragma unroll
  for (int c = 0; c < 8; ++c) {
    float2 p = part[(long)(bh * 8 + c) * 64 + d];
    float nm = fmaxf(m, p.x);
    s = s * __expf(m - nm) + p.y * __expf(p.x - nm);
    m = nm;
  }
  stat[bh * 64 + d] = make_float2(m, 1.0f / s);
}

// ---------------------------------------------------------------- kv = sum_s softmax_k[s,d] * v[s,e]  (partials over s-chunks)
__global__ __launch_bounds__(256) void kv_partial(const bf16_t* __restrict__ qkv,
                                                  const float2* __restrict__ stat,
                                                  float* __restrict__ kvp) {
  int bh = blockIdx.x, ch = blockIdx.y;
  int b = bh >> 4, h = bh & 15;
  int t = threadIdx.x;
  __shared__ float  Kexp[64][65];
  __shared__ bf16_t Vs[64][72];
  __shared__ float  kmaxs[64], kinvs[64];
  if (t < 64) { float2 p = stat[bh * 64 + t]; kmaxs[t] = p.x; kinvs[t] = p.y; }
  int rowl = t >> 2, c0 = (t & 3) * 16;
  int dd = t >> 2, e0 = (t & 3) * 16;
  float acc[16] = {};
  for (int sb = 0; sb < 8; ++sb) {
    long s = (long)ch * 512 + sb * 64 + rowl;
    const bf16_t* base = qkv + ((long)b * SS + s) * 3072 + h * 64;
    bf16x8 k0 = *(const bf16x8*)(base + 1024 + c0);
    bf16x8 k1 = *(const bf16x8*)(base + 1024 + c0 + 8);
    bf16x8 v0 = *(const bf16x8*)(base + 2048 + c0);
    bf16x8 v1 = *(const bf16x8*)(base + 2048 + c0 + 8);
    __syncthreads();
    #pragma unroll
    for (int j = 0; j < 8; ++j) {
      Kexp[rowl][c0 + j]     = __expf((float)k0[j] - kmaxs[c0 + j]) * kinvs[c0 + j];
      Kexp[rowl][c0 + 8 + j] = __expf((float)k1[j] - kmaxs[c0 + 8 + j]) * kinvs[c0 + 8 + j];
    }
    *(bf16x8*)&Vs[rowl][c0]     = v0;
    *(bf16x8*)&Vs[rowl][c0 + 8] = v1;
    __syncthreads();
    for (int ls = 0; ls < 64; ++ls) {
      float kd = Kexp[ls][dd];
      bf16x8 va = *(const bf16x8*)&Vs[ls][e0];
      bf16x8 vb = *(const bf16x8*)&Vs[ls][e0 + 8];
      #pragma unroll
      for (int j = 0; j < 8; ++j) {
        acc[j]     += kd * (float)va[j];
        acc[j + 8] += kd * (float)vb[j];
      }
    }
  }
  float* dst = kvp + (long)(bh * 8 + ch) * 4096 + dd * 64 + e0;
  #pragma unroll
  for (int j = 0; j < 16; ++j) dst[j] = acc[j];
}

// reduce partials, store TRANSPOSED bf16: kvT[bh][e][d]
__global__ void kv_reduce(const float* __restrict__ kvp, bf16_t* __restrict__ kvT) {
  int bh = blockIdx.x, t = threadIdx.x;
  for (int p = t; p < 4096; p += 256) {
    int d = p >> 6, e = p & 63;
    float s = 0.f;
    #pragma unroll
    for (int c = 0; c < 8; ++c) s += kvp[(long)(bh * 8 + c) * 4096 + p];
    kvT[(long)bh * 4096 + e * 64 + d] = (bf16_t)s;
  }
}

// ---------------------------------------------------------------- out[s,e] = q_sm[s,:] @ kv[:,e]  via MFMA, per (b,h)
__global__ __launch_bounds__(256) void attn_apply(const bf16_t* __restrict__ qkv,
                                                  const bf16_t* __restrict__ kvT,
                                                  bf16_t* __restrict__ attn) {
  int bh = blockIdx.x, sc = blockIdx.y;
  int b = bh >> 4, h = bh & 15;
  int t = threadIdx.x, lane = t & 63, w = t >> 6;
  __shared__ bf16_t kvs[64 * 64];
  for (int i = t * 8; i < 4096; i += 256 * 8)
    *(bf16x8*)&kvs[i] = *(const bf16x8*)(kvT + (long)bh * 4096 + i);
  __syncthreads();
  int fr = lane & 15, kq = (lane >> 4) * 8;
  long qrow = (long)b * SS + sc * 128 + w * 32;
  f32x4 acc[2][4] = {};
  #pragma unroll
  for (int kk = 0; kk < 2; ++kk) {
    bf16x8 a0 = *(const bf16x8*)(qkv + (qrow + fr) * 3072      + h * 64 + kk * 32 + kq);
    bf16x8 a1 = *(const bf16x8*)(qkv + (qrow + 16 + fr) * 3072 + h * 64 + kk * 32 + kq);
    #pragma unroll
    for (int j = 0; j < 4; ++j) {
      bf16x8 bfr = *(const bf16x8*)&kvs[(j * 16 + fr) * 64 + kk * 32 + kq];
      acc[0][j] = __builtin_amdgcn_mfma_f32_16x16x32_bf16(a0, bfr, acc[0][j], 0, 0, 0);
      acc[1][j] = __builtin_amdgcn_mfma_f32_16x16x32_bf16(a1, bfr, acc[1][j], 0, 0, 0);
    }
  }
  int rq = (lane >> 4) * 4;
  #pragma unroll
  for (int i = 0; i < 2; ++i)
    #pragma unroll
    for (int j = 0; j < 4; ++j)
      #pragma unroll
      for (int r = 0; r < 4; ++r)
        attn[(qrow + i * 16 + rq + r) * 1024 + h * 64 + j * 16 + fr] = (bf16_t)acc[i][j][r];
}

// ---------------------------------------------------------------- launch
extern "C" void kernel_launch(void* const* d_in, const int* in_sizes, int n_in,
                              void* d_out, int out_size, void* d_ws, size_t ws_size,
                              hipStream_t stream) {
  (void)in_sizes; (void)n_in; (void)out_size; (void)ws_size;
  const float* x      = (const float*)d_in[0];
  const float* w_qkv  = (const float*)d_in[1];
  const float* b_qkv  = (const float*)d_in[2];
  const float* w_out  = (const float*)d_in[3];
  const float* b_out  = (const float*)d_in[4];
  const float* w_ffn1 = (const float*)d_in[5];
  const float* b_ffn1 = (const float*)d_in[6];
  const float* w_ffn2 = (const float*)d_in[7];
  const float* b_ffn2 = (const float*)d_in[8];
  const float* g1     = (const float*)d_in[9];
  const float* be1    = (const float*)d_in[10];
  const float* g2     = (const float*)d_in[11];
  const float* be2    = (const float*)d_in[12];

  // ---------------- workspace layout (total ≈ 160.8 MB) ----------------
  char* ws = (char*)d_ws;
  constexpr size_t WT_QKV_OFF  = 0;
  constexpr size_t WT_OUT_OFF  = WT_QKV_OFF  + 6291456;
  constexpr size_t WT_FFN1_OFF = WT_OUT_OFF  + 2097152;
  constexpr size_t WT_FFN2_OFF = WT_FFN1_OFF + 8388608;
  constexpr size_t KSTATP_OFF  = WT_FFN2_OFF + 8388608;
  constexpr size_t KSTAT_OFF   = KSTATP_OFF  + 262144;
  constexpr size_t KVP_OFF     = KSTAT_OFF   + 32768;
  constexpr size_t KVT_OFF     = KVP_OFF     + 8388608;
  constexpr size_t ACT1_OFF    = KVT_OFF     + 524288;
  constexpr size_t BIG_OFF     = ACT1_OFF    + 33554432;

  bf16_t* WT_QKV  = (bf16_t*)(ws + WT_QKV_OFF);
  bf16_t* WT_OUT  = (bf16_t*)(ws + WT_OUT_OFF);
  bf16_t* WT_FFN1 = (bf16_t*)(ws + WT_FFN1_OFF);
  bf16_t* WT_FFN2 = (bf16_t*)(ws + WT_FFN2_OFF);
  float2* KSTATP  = (float2*)(ws + KSTATP_OFF);
  float2* KSTAT   = (float2*)(ws + KSTAT_OFF);
  float*  KVP     = (float*) (ws + KVP_OFF);
  bf16_t* KVT     = (bf16_t*)(ws + KVT_OFF);
  bf16_t* ACT1    = (bf16_t*)(ws + ACT1_OFF);
  bf16_t* QKV     = (bf16_t*)(ws + BIG_OFF);   // 96 MB
  bf16_t* GACT    = (bf16_t*)(ws + BIG_OFF);   // 64 MB chunk, after QKV dead
  float*  Y       = (float*)  d_out;           // residual mid-buffer lives in d_out

  wtrans<<<dim3(3072 / 32, 1024 / 32), dim3(32, 8), 0, stream>>>(w_qkv,  WT_QKV,  1024, 3072);
  wtrans<<<dim3(1024 / 32, 1024 / 32), dim3(32, 8), 0, stream>>>(w_out,  WT_OUT,  1024, 1024);
  wtrans<<<dim3(4096 / 32, 1024 / 32), dim3(32, 8), 0, stream>>>(w_ffn1, WT_FFN1, 1024, 4096);
  wtrans<<<dim3(1024 / 32, 4096 / 32), dim3(32, 8), 0, stream>>>(w_ffn2, WT_FFN2, 4096, 1024);

  ln_kernel<<<NROWS, 256, 0, stream>>>(x, g1, be1, ACT1);

  // qkv = ln1 @ WqkvT + b
  gemm256<0><<<dim3(3072 / 256, NROWS / 256), 512, 0, stream>>>(ACT1, WT_QKV, b_qkv, nullptr, QKV, NROWS, 3072, 1024);

  qsoftmax<<<NROWS, 256, 0, stream>>>(QKV);
  kstats_partial<<<dim3(64, 8), 256, 0, stream>>>(QKV, KSTATP);
  kstats_merge<<<64, 64, 0, stream>>>(KSTATP, KSTAT);
  kv_partial<<<dim3(64, 8), 256, 0, stream>>>(QKV, KSTAT, KVP);
  kv_reduce<<<64, 256, 0, stream>>>(KVP, KVT);
  attn_apply<<<dim3(64, SS / 128), 256, 0, stream>>>(QKV, KVT, ACT1);

  // y = x + attn_cat @ WoutT + b  -> d_out
  gemm256<1><<<dim3(1024 / 256, NROWS / 256), 512, 0, stream>>>(ACT1, WT_OUT, b_out, x, Y, NROWS, 1024, 1024);

  ln_kernel<<<NROWS, 256, 0, stream>>>(Y, g2, be2, ACT1);

  // FFN in two 8192-row chunks; ffn2 overwrites d_out with final result
  for (int c = 0; c < 2; ++c) {
    const long r0 = (long)c * 8192;
    gemm256<2><<<dim3(4096 / 256, 8192 / 256), 512, 0, stream>>>(
        ACT1 + r0 * 1024, WT_FFN1, b_ffn1, nullptr, GACT, 8192, 4096, 1024);
    gemm256<1><<<dim3(1024 / 256, 8192 / 256), 512, 0, stream>>>(
        GACT, WT_FFN2, b_ffn2, x + r0 * 1024, (float*)d_out + r0 * 1024, 8192, 1024, 4096);
  }
}

// Round 6
// 745.039 us; speedup vs baseline: 1.0985x; 1.0985x over previous
//
#include <hip/hip_runtime.h>
#include <hip/hip_bf16.h>
#include <cstdint>
#include <cstddef>

#define DIMC 1024
#define HEADS 16
#define HD 64
#define DFF 4096
#define BB 4
#define SS 4096
#define NROWS (BB*SS)   // 16384

typedef __bf16 bf16_t;
typedef __bf16 bf16x8 __attribute__((ext_vector_type(8)));
typedef __bf16 bf16x4 __attribute__((ext_vector_type(4)));
typedef float  f32x4  __attribute__((ext_vector_type(4)));

#define GLDS16(gp, lp) \
  __builtin_amdgcn_global_load_lds((const __attribute__((address_space(1))) void*)(gp), \
                                   (__attribute__((address_space(3))) void*)(lp), 16, 0, 0)

#define MFMA16(a, b, c) __builtin_amdgcn_mfma_f32_16x16x32_bf16((a), (b), (c), 0, 0, 0)

// ---------------------------------------------------------------- weight transpose f32[K][N] -> bf16[N][K]
__global__ __launch_bounds__(256) void wtrans(const float* __restrict__ W, bf16_t* __restrict__ Wt,
                                              int K, int N) {
  __shared__ float tile[32][33];
  int c0 = blockIdx.x * 32, r0 = blockIdx.y * 32;
  int tx = threadIdx.x, ty = threadIdx.y;
  #pragma unroll
  for (int i = 0; i < 32; i += 8)
    tile[ty + i][tx] = W[(long)(r0 + ty + i) * N + c0 + tx];
  __syncthreads();
  #pragma unroll
  for (int i = 0; i < 32; i += 8)
    Wt[(long)(c0 + ty + i) * K + r0 + tx] = (bf16_t)tile[tx][ty + i];
}

// ---------------------------------------------------------------- LayerNorm f32 row -> bf16 row
__global__ __launch_bounds__(256) void ln_kernel(const float* __restrict__ in,
                                                 const float* __restrict__ gamma,
                                                 const float* __restrict__ beta,
                                                 bf16_t* __restrict__ out) {
  long r = blockIdx.x;
  int t = threadIdx.x;
  float4 v = ((const float4*)(in + r * DIMC))[t];
  float s  = v.x + v.y + v.z + v.w;
  float sq = v.x * v.x + v.y * v.y + v.z * v.z + v.w * v.w;
  #pragma unroll
  for (int o = 32; o > 0; o >>= 1) { s += __shfl_xor(s, o); sq += __shfl_xor(sq, o); }
  __shared__ float red[8];
  if ((t & 63) == 0) { red[(t >> 6) * 2] = s; red[(t >> 6) * 2 + 1] = sq; }
  __syncthreads();
  s  = red[0] + red[2] + red[4] + red[6];
  sq = red[1] + red[3] + red[5] + red[7];
  float mu  = s * (1.0f / DIMC);
  float var = sq * (1.0f / DIMC) - mu * mu;
  float rs  = 1.0f / sqrtf(var + 1e-5f);
  float4 g  = ((const float4*)gamma)[t];
  float4 bb = ((const float4*)beta)[t];
  bf16x4 o;
  o[0] = (bf16_t)((v.x - mu) * rs * g.x + bb.x);
  o[1] = (bf16_t)((v.y - mu) * rs * g.y + bb.y);
  o[2] = (bf16_t)((v.z - mu) * rs * g.z + bb.z);
  o[3] = (bf16_t)((v.w - mu) * rs * g.w + bb.w);
  ((bf16x4*)(out + r * DIMC))[t] = o;
}

// ---------------------------------------------------------------- 256x256 GEMM, 8 waves, BK=64, 4-phase interleave + derived vmcnt
// A[M][K] bf16 @ Bt[N][K] bf16.  MODE 0: bf16=acc+bias  MODE 1: f32=acc+bias+resid  MODE 2: bf16=gelu(acc+bias)
template <int MODE>
__global__ __launch_bounds__(512, 2) void gemm256(const bf16_t* __restrict__ A,
                                                  const bf16_t* __restrict__ Bt,
                                                  const float* __restrict__ bias,
                                                  const float* __restrict__ resid,
                                                  void* __restrict__ outp,
                                                  int M, int N, int K) {
  // [slot][khalf][op A=0/B=1][row][32 cols bf16] = 128 KiB.  Unit (kh,op) = one linear gload_lds region.
  __shared__ bf16_t lds[2][2][2][256][32];
  const int tid  = threadIdx.x;
  const int lane = tid & 63;
  const int wr   = (tid >> 6) >> 2;   // 0..1  M-half
  const int wc   = (tid >> 6) & 3;    // 0..3  N-quarter
  const long arow0 = (long)blockIdx.y * 256;
  const long brow0 = (long)blockIdx.x * 256;
  const int fr = lane & 15;
  const int q4 = lane >> 4;           // chunk within k-half

  const int srow = tid >> 2;          // staging row 0..127 (then +128)
  const int sc   = tid & 3;           // staging chunk within k-half

  f32x4 acc[8][4] = {};
  bf16x8 bf[4];
  const int NT = K >> 6;

  // stage unit u (0:A-kh0, 1:B-kh0, 2:A-kh1, 3:B-kh1) of K-tile kt into slot s.
  // LDS dest linear per-lane; global source chunk XOR'd (same permutation the reads apply).
  auto STAGE_UNIT = [&](int kt, int u, int s) {
    const int op = u & 1;
    const int kh = u >> 1;
    const bf16_t* gbase = (op ? Bt : A) + (op ? brow0 : arow0) * (long)K + (kt << 6) + kh * 32;
    #pragma unroll
    for (int p = 0; p < 2; ++p) {
      const int row = p * 128 + srow;
      const int gch = sc ^ ((row >> 1) & 3);
      GLDS16(gbase + (long)row * K + gch * 8, &lds[s][kh][op][row][sc * 8]);
    }
  };
  auto LDA = [&](int s, int ks, int i) -> bf16x8 {
    const int row = wr * 128 + i * 16 + fr;
    return *(const bf16x8*)&lds[s][ks][0][row][(q4 ^ ((row >> 1) & 3)) * 8];
  };
  auto LDB = [&](int s, int ks, int j) -> bf16x8 {
    const int row = wc * 64 + j * 16 + fr;
    return *(const bf16x8*)&lds[s][ks][1][row][(q4 ^ ((row >> 1) & 3)) * 8];
  };

#define PHASE(PH, KS, I0, READB, VM)                                          \
  {                                                                           \
    if (t + 1 < NT) STAGE_UNIT(t + 1, PH, s ^ 1);                             \
    bf16x8 a0 = LDA(s, KS, I0 + 0), a1 = LDA(s, KS, I0 + 1),                  \
           a2 = LDA(s, KS, I0 + 2), a3 = LDA(s, KS, I0 + 3);                  \
    if (READB) {                                                              \
      bf[0] = LDB(s, KS, 0); bf[1] = LDB(s, KS, 1);                           \
      bf[2] = LDB(s, KS, 2); bf[3] = LDB(s, KS, 3);                           \
    }                                                                         \
    if (VM) {                                                                 \
      if (t + 1 < NT) asm volatile("s_waitcnt vmcnt(4)" ::: "memory");        \
      else            asm volatile("s_waitcnt vmcnt(0)" ::: "memory");        \
    }                                                                         \
    __builtin_amdgcn_sched_barrier(0);                                        \
    __builtin_amdgcn_s_barrier();                                             \
    __builtin_amdgcn_sched_barrier(0);                                        \
    __builtin_amdgcn_s_setprio(1);                                            \
    acc[I0+0][0] = MFMA16(a0, bf[0], acc[I0+0][0]);                           \
    acc[I0+0][1] = MFMA16(a0, bf[1], acc[I0+0][1]);                           \
    acc[I0+0][2] = MFMA16(a0, bf[2], acc[I0+0][2]);                           \
    acc[I0+0][3] = MFMA16(a0, bf[3], acc[I0+0][3]);                           \
    acc[I0+1][0] = MFMA16(a1, bf[0], acc[I0+1][0]);                           \
    acc[I0+1][1] = MFMA16(a1, bf[1], acc[I0+1][1]);                           \
    acc[I0+1][2] = MFMA16(a1, bf[2], acc[I0+1][2]);                           \
    acc[I0+1][3] = MFMA16(a1, bf[3], acc[I0+1][3]);                           \
    acc[I0+2][0] = MFMA16(a2, bf[0], acc[I0+2][0]);                           \
    acc[I0+2][1] = MFMA16(a2, bf[1], acc[I0+2][1]);                           \
    acc[I0+2][2] = MFMA16(a2, bf[2], acc[I0+2][2]);                           \
    acc[I0+2][3] = MFMA16(a2, bf[3], acc[I0+2][3]);                           \
    acc[I0+3][0] = MFMA16(a3, bf[0], acc[I0+3][0]);                           \
    acc[I0+3][1] = MFMA16(a3, bf[1], acc[I0+3][1]);                           \
    acc[I0+3][2] = MFMA16(a3, bf[2], acc[I0+3][2]);                           \
    acc[I0+3][3] = MFMA16(a3, bf[3], acc[I0+3][3]);                           \
    __builtin_amdgcn_s_setprio(0);                                            \
    __builtin_amdgcn_sched_barrier(0);                                        \
    __builtin_amdgcn_s_barrier();                                             \
    __builtin_amdgcn_sched_barrier(0);                                        \
  }

  // prologue: full tile 0 staged (A0,B0,A1,B1 = 8 loads); A0,B0 must land before P0 reads
  STAGE_UNIT(0, 0, 0); STAGE_UNIT(0, 1, 0); STAGE_UNIT(0, 2, 0); STAGE_UNIT(0, 3, 0);
  asm volatile("s_waitcnt vmcnt(4)" ::: "memory");
  __builtin_amdgcn_sched_barrier(0);
  __builtin_amdgcn_s_barrier();
  __builtin_amdgcn_sched_barrier(0);

  for (int t = 0; t < NT; ++t) {
    const int s = t & 1;
    PHASE(0, 0, 0, 1, 0)   // read B[ks0]+A[Mh0,ks0], stage A-kh0(t+1)
    PHASE(1, 0, 4, 0, 1)   // read A[Mh1,ks0],        stage B-kh0(t+1), vmcnt guards kh1(t)
    PHASE(2, 1, 0, 1, 0)   // read B[ks1]+A[Mh0,ks1], stage A-kh1(t+1)
    PHASE(3, 1, 4, 0, 1)   // read A[Mh1,ks1],        stage B-kh1(t+1), vmcnt guards kh0(t+1)
  }
#undef PHASE

  const int rq = q4 * 4;
  #pragma unroll
  for (int i = 0; i < 8; ++i) {
    #pragma unroll
    for (int j = 0; j < 4; ++j) {
      long col = brow0 + wc * 64 + j * 16 + fr;
      float bv = bias[col];
      #pragma unroll
      for (int r = 0; r < 4; ++r) {
        long row = arow0 + wr * 128 + i * 16 + rq + r;
        float v = acc[i][j][r] + bv;
        if (MODE == 0) {
          ((bf16_t*)outp)[row * N + col] = (bf16_t)v;
        } else if (MODE == 1) {
          ((float*)outp)[row * N + col] = v + resid[row * N + col];
        } else {
          float g = 0.5f * v * (1.0f + erff(v * 0.70710678118654752f));
          ((bf16_t*)outp)[row * N + col] = (bf16_t)g;
        }
      }
    }
  }
}

// ---------------------------------------------------------------- q softmax (in-place, per (row, head) over 64)
__global__ __launch_bounds__(256) void qsoftmax(bf16_t* __restrict__ qkv) {
  long r = blockIdx.x;
  int t = threadIdx.x, h = t >> 4, l = t & 15;
  bf16_t* p = qkv + r * 3072 + h * 64 + l * 4;
  bf16x4 v4 = *(const bf16x4*)p;
  float v0 = v4[0], v1 = v4[1], v2 = v4[2], v3 = v4[3];
  float m = fmaxf(fmaxf(v0, v1), fmaxf(v2, v3));
  #pragma unroll
  for (int o = 8; o >= 1; o >>= 1) m = fmaxf(m, __shfl_xor(m, o));
  float e0 = __expf(v0 - m), e1 = __expf(v1 - m), e2 = __expf(v2 - m), e3 = __expf(v3 - m);
  float s = e0 + e1 + e2 + e3;
  #pragma unroll
  for (int o = 8; o >= 1; o >>= 1) s += __shfl_xor(s, o);
  float inv = 1.0f / s;
  bf16x4 o4;
  o4[0] = (bf16_t)(e0 * inv); o4[1] = (bf16_t)(e1 * inv);
  o4[2] = (bf16_t)(e2 * inv); o4[3] = (bf16_t)(e3 * inv);
  *(bf16x4*)p = o4;
}

// ---------------------------------------------------------------- k column-softmax stats (online max/sum partials)
__global__ __launch_bounds__(256) void kstats_partial(const bf16_t* __restrict__ qkv,
                                                      float2* __restrict__ part) {
  int bh = blockIdx.x, ch = blockIdx.y;
  int b = bh >> 4, h = bh & 15;
  int t = threadIdx.x, d = t & 63, sr = t >> 6;
  const bf16_t* kp = qkv + (long)b * SS * 3072 + 1024 + h * 64 + d;
  float m = -INFINITY, sum = 0.f;
  for (int s = ch * 512 + sr; s < ch * 512 + 512; s += 4) {
    float v = (float)kp[(long)s * 3072];
    float nm = fmaxf(m, v);
    sum = sum * __expf(m - nm) + __expf(v - nm);
    m = nm;
  }
  __shared__ float2 red[4][64];
  red[sr][d] = make_float2(m, sum);
  __syncthreads();
  if (t < 64) {
    float2 a = red[0][t];
    #pragma unroll
    for (int i = 1; i < 4; ++i) {
      float2 p = red[i][t];
      float nm = fmaxf(a.x, p.x);
      a.y = a.y * __expf(a.x - nm) + p.y * __expf(p.x - nm);
      a.x = nm;
    }
    part[(long)(bh * 8 + ch) * 64 + t] = a;
  }
}

__global__ void kstats_merge(const float2* __restrict__ part, float2* __restrict__ stat) {
  int bh = blockIdx.x, d = threadIdx.x;  // 64 threads
  float m = -INFINITY, s = 0.f;
  #pragma unroll
  for (int c = 0; c < 8; ++c) {
    float2 p = part[(long)(bh * 8 + c) * 64 + d];
    float nm = fmaxf(m, p.x);
    s = s * __expf(m - nm) + p.y * __expf(p.x - nm);
    m = nm;
  }
  stat[bh * 64 + d] = make_float2(m, 1.0f / s);
}

// ---------------------------------------------------------------- kv = sum_s softmax_k[s,d] * v[s,e]  (partials over s-chunks)
__global__ __launch_bounds__(256) void kv_partial(const bf16_t* __restrict__ qkv,
                                                  const float2* __restrict__ stat,
                                                  float* __restrict__ kvp) {
  int bh = blockIdx.x, ch = blockIdx.y;
  int b = bh >> 4, h = bh & 15;
  int t = threadIdx.x;
  __shared__ float  Kexp[64][65];
  __shared__ bf16_t Vs[64][72];
  __shared__ float  kmaxs[64], kinvs[64];
  if (t < 64) { float2 p = stat[bh * 64 + t]; kmaxs[t] = p.x; kinvs[t] = p.y; }
  int rowl = t >> 2, c0 = (t & 3) * 16;
  int dd = t >> 2, e0 = (t & 3) * 16;
  float acc[16] = {};
  for (int sb = 0; sb < 8; ++sb) {
    long s = (long)ch * 512 + sb * 64 + rowl;
    const bf16_t* base = qkv + ((long)b * SS + s) * 3072 + h * 64;
    bf16x8 k0 = *(const bf16x8*)(base + 1024 + c0);
    bf16x8 k1 = *(const bf16x8*)(base + 1024 + c0 + 8);
    bf16x8 v0 = *(const bf16x8*)(base + 2048 + c0);
    bf16x8 v1 = *(const bf16x8*)(base + 2048 + c0 + 8);
    __syncthreads();
    #pragma unroll
    for (int j = 0; j < 8; ++j) {
      Kexp[rowl][c0 + j]     = __expf((float)k0[j] - kmaxs[c0 + j]) * kinvs[c0 + j];
      Kexp[rowl][c0 + 8 + j] = __expf((float)k1[j] - kmaxs[c0 + 8 + j]) * kinvs[c0 + 8 + j];
    }
    *(bf16x8*)&Vs[rowl][c0]     = v0;
    *(bf16x8*)&Vs[rowl][c0 + 8] = v1;
    __syncthreads();
    for (int ls = 0; ls < 64; ++ls) {
      float kd = Kexp[ls][dd];
      bf16x8 va = *(const bf16x8*)&Vs[ls][e0];
      bf16x8 vb = *(const bf16x8*)&Vs[ls][e0 + 8];
      #pragma unroll
      for (int j = 0; j < 8; ++j) {
        acc[j]     += kd * (float)va[j];
        acc[j + 8] += kd * (float)vb[j];
      }
    }
  }
  float* dst = kvp + (long)(bh * 8 + ch) * 4096 + dd * 64 + e0;
  #pragma unroll
  for (int j = 0; j < 16; ++j) dst[j] = acc[j];
}

// reduce partials, store TRANSPOSED bf16: kvT[bh][e][d]
__global__ void kv_reduce(const float* __restrict__ kvp, bf16_t* __restrict__ kvT) {
  int bh = blockIdx.x, t = threadIdx.x;
  for (int p = t; p < 4096; p += 256) {
    int d = p >> 6, e = p & 63;
    float s = 0.f;
    #pragma unroll
    for (int c = 0; c < 8; ++c) s += kvp[(long)(bh * 8 + c) * 4096 + p];
    kvT[(long)bh * 4096 + e * 64 + d] = (bf16_t)s;
  }
}

// ---------------------------------------------------------------- out[s,e] = q_sm[s,:] @ kv[:,e]  via MFMA, per (b,h)
__global__ __launch_bounds__(256) void attn_apply(const bf16_t* __restrict__ qkv,
                                                  const bf16_t* __restrict__ kvT,
                                                  bf16_t* __restrict__ attn) {
  int bh = blockIdx.x, sc = blockIdx.y;
  int b = bh >> 4, h = bh & 15;
  int t = threadIdx.x, lane = t & 63, w = t >> 6;
  __shared__ bf16_t kvs[64 * 64];
  for (int i = t * 8; i < 4096; i += 256 * 8)
    *(bf16x8*)&kvs[i] = *(const bf16x8*)(kvT + (long)bh * 4096 + i);
  __syncthreads();
  int fr = lane & 15, kq = (lane >> 4) * 8;
  long qrow = (long)b * SS + sc * 128 + w * 32;
  f32x4 acc[2][4] = {};
  #pragma unroll
  for (int kk = 0; kk < 2; ++kk) {
    bf16x8 a0 = *(const bf16x8*)(qkv + (qrow + fr) * 3072      + h * 64 + kk * 32 + kq);
    bf16x8 a1 = *(const bf16x8*)(qkv + (qrow + 16 + fr) * 3072 + h * 64 + kk * 32 + kq);
    #pragma unroll
    for (int j = 0; j < 4; ++j) {
      bf16x8 bfr = *(const bf16x8*)&kvs[(j * 16 + fr) * 64 + kk * 32 + kq];
      acc[0][j] = MFMA16(a0, bfr, acc[0][j]);
      acc[1][j] = MFMA16(a1, bfr, acc[1][j]);
    }
  }
  int rq = (lane >> 4) * 4;
  #pragma unroll
  for (int i = 0; i < 2; ++i)
    #pragma unroll
    for (int j = 0; j < 4; ++j)
      #pragma unroll
      for (int r = 0; r < 4; ++r)
        attn[(qrow + i * 16 + rq + r) * 1024 + h * 64 + j * 16 + fr] = (bf16_t)acc[i][j][r];
}

// ---------------------------------------------------------------- launch
extern "C" void kernel_launch(void* const* d_in, const int* in_sizes, int n_in,
                              void* d_out, int out_size, void* d_ws, size_t ws_size,
                              hipStream_t stream) {
  (void)in_sizes; (void)n_in; (void)out_size;
  const float* x      = (const float*)d_in[0];
  const float* w_qkv  = (const float*)d_in[1];
  const float* b_qkv  = (const float*)d_in[2];
  const float* w_out  = (const float*)d_in[3];
  const float* b_out  = (const float*)d_in[4];
  const float* w_ffn1 = (const float*)d_in[5];
  const float* b_ffn1 = (const float*)d_in[6];
  const float* w_ffn2 = (const float*)d_in[7];
  const float* b_ffn2 = (const float*)d_in[8];
  const float* g1     = (const float*)d_in[9];
  const float* be1    = (const float*)d_in[10];
  const float* g2     = (const float*)d_in[11];
  const float* be2    = (const float*)d_in[12];

  char* ws = (char*)d_ws;
  constexpr size_t WT_QKV_OFF  = 0;
  constexpr size_t WT_OUT_OFF  = WT_QKV_OFF  + 6291456;
  constexpr size_t WT_FFN1_OFF = WT_OUT_OFF  + 2097152;
  constexpr size_t WT_FFN2_OFF = WT_FFN1_OFF + 8388608;
  constexpr size_t KSTATP_OFF  = WT_FFN2_OFF + 8388608;
  constexpr size_t KSTAT_OFF   = KSTATP_OFF  + 262144;
  constexpr size_t KVP_OFF     = KSTAT_OFF   + 32768;
  constexpr size_t KVT_OFF     = KVP_OFF     + 8388608;
  constexpr size_t ACT1_OFF    = KVT_OFF     + 524288;
  constexpr size_t BIG_OFF     = ACT1_OFF    + 33554432;          // 67,928,064

  bf16_t* WT_QKV  = (bf16_t*)(ws + WT_QKV_OFF);
  bf16_t* WT_OUT  = (bf16_t*)(ws + WT_OUT_OFF);
  bf16_t* WT_FFN1 = (bf16_t*)(ws + WT_FFN1_OFF);
  bf16_t* WT_FFN2 = (bf16_t*)(ws + WT_FFN2_OFF);
  float2* KSTATP  = (float2*)(ws + KSTATP_OFF);
  float2* KSTAT   = (float2*)(ws + KSTAT_OFF);
  float*  KVP     = (float*) (ws + KVP_OFF);
  bf16_t* KVT     = (bf16_t*)(ws + KVT_OFF);
  bf16_t* ACT1    = (bf16_t*)(ws + ACT1_OFF);
  bf16_t* QKV     = (bf16_t*)(ws + BIG_OFF);   // 96 MB
  bf16_t* GACT    = (bf16_t*)(ws + BIG_OFF);   // up to 128 MB, after QKV dead
  float*  Y       = (float*)  d_out;           // residual mid-buffer lives in d_out

  // full (unchunked) FFN needs BIG = 128 MB -> total 202,145,792 B
  const bool big_ws = ws_size >= (size_t)(BIG_OFF + 134217728ull);

  wtrans<<<dim3(3072 / 32, 1024 / 32), dim3(32, 8), 0, stream>>>(w_qkv,  WT_QKV,  1024, 3072);
  wtrans<<<dim3(1024 / 32, 1024 / 32), dim3(32, 8), 0, stream>>>(w_out,  WT_OUT,  1024, 1024);
  wtrans<<<dim3(4096 / 32, 1024 / 32), dim3(32, 8), 0, stream>>>(w_ffn1, WT_FFN1, 1024, 4096);
  wtrans<<<dim3(1024 / 32, 4096 / 32), dim3(32, 8), 0, stream>>>(w_ffn2, WT_FFN2, 4096, 1024);

  ln_kernel<<<NROWS, 256, 0, stream>>>(x, g1, be1, ACT1);

  // qkv = ln1 @ WqkvT + b
  gemm256<0><<<dim3(3072 / 256, NROWS / 256), 512, 0, stream>>>(ACT1, WT_QKV, b_qkv, nullptr, QKV, NROWS, 3072, 1024);

  qsoftmax<<<NROWS, 256, 0, stream>>>(QKV);
  kstats_partial<<<dim3(64, 8), 256, 0, stream>>>(QKV, KSTATP);
  kstats_merge<<<64, 64, 0, stream>>>(KSTATP, KSTAT);
  kv_partial<<<dim3(64, 8), 256, 0, stream>>>(QKV, KSTAT, KVP);
  kv_reduce<<<64, 256, 0, stream>>>(KVP, KVT);
  attn_apply<<<dim3(64, SS / 128), 256, 0, stream>>>(QKV, KVT, ACT1);

  // y = x + attn_cat @ WoutT + b  -> d_out  (QKV now dead)
  gemm256<1><<<dim3(1024 / 256, NROWS / 256), 512, 0, stream>>>(ACT1, WT_OUT, b_out, x, Y, NROWS, 1024, 1024);

  ln_kernel<<<NROWS, 256, 0, stream>>>(Y, g2, be2, ACT1);

  if (big_ws) {
    // full-width FFN: ffn1 grid 16x64 (1024 blocks), ffn2 grid 4x64 (256 blocks, full GPU)
    gemm256<2><<<dim3(4096 / 256, NROWS / 256), 512, 0, stream>>>(ACT1, WT_FFN1, b_ffn1, nullptr, GACT, NROWS, 4096, 1024);
    gemm256<1><<<dim3(1024 / 256, NROWS / 256), 512, 0, stream>>>(GACT, WT_FFN2, b_ffn2, x, (float*)d_out, NROWS, 1024, 4096);
  } else {
    // fallback: two 8192-row chunks (GACT 64 MB)
    for (int c = 0; c < 2; ++c) {
      const long r0 = (long)c * 8192;
      gemm256<2><<<dim3(4096 / 256, 8192 / 256), 512, 0, stream>>>(
          ACT1 + r0 * 1024, WT_FFN1, b_ffn1, nullptr, GACT, 8192, 4096, 1024);
      gemm256<1><<<dim3(1024 / 256, 8192 / 256), 512, 0, stream>>>(
          GACT, WT_FFN2, b_ffn2, x + r0 * 1024, (float*)d_out + r0 * 1024, 8192, 1024, 4096);
    }
  }
}

// Round 7
// 735.336 us; speedup vs baseline: 1.1130x; 1.0132x over previous
//
#include <hip/hip_runtime.h>
#include <hip/hip_bf16.h>
#include <cstdint>
#include <cstddef>

#define DIMC 1024
#define HEADS 16
#define HD 64
#define DFF 4096
#define BB 4
#define SS 4096
#define NROWS (BB*SS)   // 16384

typedef __bf16 bf16_t;
typedef __bf16 bf16x8 __attribute__((ext_vector_type(8)));
typedef __bf16 bf16x4 __attribute__((ext_vector_type(4)));
typedef float  f32x4  __attribute__((ext_vector_type(4)));

#define GLDS16(gp, lp) \
  __builtin_amdgcn_global_load_lds((const __attribute__((address_space(1))) void*)(gp), \
                                   (__attribute__((address_space(3))) void*)(lp), 16, 0, 0)

#define MFMA16(a, b, c) __builtin_amdgcn_mfma_f32_16x16x32_bf16((a), (b), (c), 0, 0, 0)

// ---------------------------------------------------------------- weight transpose f32[K][N] -> bf16[N][K]
__global__ __launch_bounds__(256) void wtrans(const float* __restrict__ W, bf16_t* __restrict__ Wt,
                                              int K, int N) {
  __shared__ float tile[32][33];
  int c0 = blockIdx.x * 32, r0 = blockIdx.y * 32;
  int tx = threadIdx.x, ty = threadIdx.y;
  #pragma unroll
  for (int i = 0; i < 32; i += 8)
    tile[ty + i][tx] = W[(long)(r0 + ty + i) * N + c0 + tx];
  __syncthreads();
  #pragma unroll
  for (int i = 0; i < 32; i += 8)
    Wt[(long)(c0 + ty + i) * K + r0 + tx] = (bf16_t)tile[tx][ty + i];
}

// ---------------------------------------------------------------- LayerNorm f32 row -> bf16 row
__global__ __launch_bounds__(256) void ln_kernel(const float* __restrict__ in,
                                                 const float* __restrict__ gamma,
                                                 const float* __restrict__ beta,
                                                 bf16_t* __restrict__ out) {
  long r = blockIdx.x;
  int t = threadIdx.x;
  float4 v = ((const float4*)(in + r * DIMC))[t];
  float s  = v.x + v.y + v.z + v.w;
  float sq = v.x * v.x + v.y * v.y + v.z * v.z + v.w * v.w;
  #pragma unroll
  for (int o = 32; o > 0; o >>= 1) { s += __shfl_xor(s, o); sq += __shfl_xor(sq, o); }
  __shared__ float red[8];
  if ((t & 63) == 0) { red[(t >> 6) * 2] = s; red[(t >> 6) * 2 + 1] = sq; }
  __syncthreads();
  s  = red[0] + red[2] + red[4] + red[6];
  sq = red[1] + red[3] + red[5] + red[7];
  float mu  = s * (1.0f / DIMC);
  float var = sq * (1.0f / DIMC) - mu * mu;
  float rs  = 1.0f / sqrtf(var + 1e-5f);
  float4 g  = ((const float4*)gamma)[t];
  float4 bb = ((const float4*)beta)[t];
  bf16x4 o;
  o[0] = (bf16_t)((v.x - mu) * rs * g.x + bb.x);
  o[1] = (bf16_t)((v.y - mu) * rs * g.y + bb.y);
  o[2] = (bf16_t)((v.z - mu) * rs * g.z + bb.z);
  o[3] = (bf16_t)((v.w - mu) * rs * g.w + bb.w);
  ((bf16x4*)(out + r * DIMC))[t] = o;
}

// ---------------------------------------------------------------- 256x256 GEMM, 8 waves, BK=64, 4-phase interleave,
// derived vmcnt, HOISTED addresses (all LDS accesses = 2 base regs + compile-time imm offsets).
// LDS layout [op][slot][kh][256][32]: op stride 64KiB, slot 32KiB, kh 16KiB, row 64B.
// Swizzle term (row>>1)&3 == (fr>>1)&3 (lane-constant) because i*16, wr*128, wc*64, p*128 are all 0 mod 4 rows.
template <int MODE>
__global__ __launch_bounds__(512, 2) void gemm256(const bf16_t* __restrict__ A,
                                                  const bf16_t* __restrict__ Bt,
                                                  const float* __restrict__ bias,
                                                  const float* __restrict__ resid,
                                                  void* __restrict__ outp,
                                                  int M, int N, int K) {
  __shared__ bf16_t lds[2][2][2][256][32];   // 128 KiB
  const int tid  = threadIdx.x;
  const int lane = tid & 63;
  const int wr   = (tid >> 6) >> 2;   // 0..1  M-half
  const int wc   = (tid >> 6) & 3;    // 0..3  N-quarter
  const long arow0 = (long)blockIdx.y * 256;
  const long brow0 = (long)blockIdx.x * 256;
  const int fr = lane & 15;
  const int q4 = lane >> 4;

  const int srow = tid >> 2;          // staging row 0..127 (then +128)
  const int sc   = tid & 3;           // staging 16B chunk within k-half
  const int gch  = sc ^ ((srow >> 1) & 3);          // lane-constant source chunk
  const int swzB = (q4 ^ ((fr >> 1) & 3)) * 16;     // lane-constant read swizzle (bytes)

  char* const ldsB  = (char*)&lds[0][0][0][0][0];
  const char* aRead = ldsB +         (wr * 128 + fr) * 64 + swzB;
  const char* bRead = ldsB + 65536 + (wc * 64  + fr) * 64 + swzB;
  char* const dstA  = ldsB + srow * 64 + sc * 16;   // == ldsB + tid*16 (linear, gload_lds-safe)
  char* const dstB  = dstA + 65536;

  const long rs128 = 128 * (long)K;
  const bf16_t* gA = A  + (arow0 + srow) * (long)K + gch * 8;
  const bf16_t* gB = Bt + (brow0 + srow) * (long)K + gch * 8;

  f32x4 acc[8][4] = {};
  bf16x8 bf[4];
  const int NT = K >> 6;              // even for all shapes here (16 or 64)

  // stage unit U (0:A-kh0 1:B-kh0 2:A-kh1 3:B-kh1) of the tile gA/gB point at, into slot DS.
#define STAGE_U(U, DS)                                                         \
  {                                                                            \
    constexpr int op_ = (U) & 1, kh_ = (U) >> 1;                               \
    const bf16_t* g_ = (op_ ? gB : gA) + kh_ * 32;                             \
    char* d_ = (op_ ? dstB : dstA) + (DS) * 32768 + kh_ * 16384;               \
    GLDS16(g_, d_);                                                            \
    GLDS16(g_ + rs128, d_ + 8192);                                             \
  }

#define LDA8(S, KS, I) (*(const bf16x8*)(aRead + (S) * 32768 + (KS) * 16384 + (I) * 1024))
#define LDB8(S, KS, J) (*(const bf16x8*)(bRead + (S) * 32768 + (KS) * 16384 + (J) * 1024))

#define PHASE(S, U, KS, I0, READB, VMF, DOSTAGE, MORE)                        \
  {                                                                           \
    if (DOSTAGE) STAGE_U(U, (S) ^ 1)                                          \
    bf16x8 a0 = LDA8(S, KS, I0 + 0), a1 = LDA8(S, KS, I0 + 1),                \
           a2 = LDA8(S, KS, I0 + 2), a3 = LDA8(S, KS, I0 + 3);                \
    if (READB) {                                                              \
      bf[0] = LDB8(S, KS, 0); bf[1] = LDB8(S, KS, 1);                         \
      bf[2] = LDB8(S, KS, 2); bf[3] = LDB8(S, KS, 3);                         \
    }                                                                         \
    if (VMF) {                                                                \
      if (MORE) asm volatile("s_waitcnt vmcnt(4)" ::: "memory");              \
      else      asm volatile("s_waitcnt vmcnt(0)" ::: "memory");              \
    }                                                                         \
    __builtin_amdgcn_sched_barrier(0);                                        \
    __builtin_amdgcn_s_barrier();                                             \
    __builtin_amdgcn_sched_barrier(0);                                        \
    __builtin_amdgcn_s_setprio(1);                                            \
    acc[I0+0][0] = MFMA16(a0, bf[0], acc[I0+0][0]);                           \
    acc[I0+0][1] = MFMA16(a0, bf[1], acc[I0+0][1]);                           \
    acc[I0+0][2] = MFMA16(a0, bf[2], acc[I0+0][2]);                           \
    acc[I0+0][3] = MFMA16(a0, bf[3], acc[I0+0][3]);                           \
    acc[I0+1][0] = MFMA16(a1, bf[0], acc[I0+1][0]);                           \
    acc[I0+1][1] = MFMA16(a1, bf[1], acc[I0+1][1]);                           \
    acc[I0+1][2] = MFMA16(a1, bf[2], acc[I0+1][2]);                           \
    acc[I0+1][3] = MFMA16(a1, bf[3], acc[I0+1][3]);                           \
    acc[I0+2][0] = MFMA16(a2, bf[0], acc[I0+2][0]);                           \
    acc[I0+2][1] = MFMA16(a2, bf[1], acc[I0+2][1]);                           \
    acc[I0+2][2] = MFMA16(a2, bf[2], acc[I0+2][2]);                           \
    acc[I0+2][3] = MFMA16(a2, bf[3], acc[I0+2][3]);                           \
    acc[I0+3][0] = MFMA16(a3, bf[0], acc[I0+3][0]);                           \
    acc[I0+3][1] = MFMA16(a3, bf[1], acc[I0+3][1]);                           \
    acc[I0+3][2] = MFMA16(a3, bf[2], acc[I0+3][2]);                           \
    acc[I0+3][3] = MFMA16(a3, bf[3], acc[I0+3][3]);                           \
    __builtin_amdgcn_s_setprio(0);                                            \
    __builtin_amdgcn_sched_barrier(0);                                        \
    __builtin_amdgcn_s_barrier();                                             \
    __builtin_amdgcn_sched_barrier(0);                                        \
  }

  // prologue: stage tile 0 fully into slot 0; wait for its kh0 half; advance to tile 1
  STAGE_U(0, 0) STAGE_U(1, 0) STAGE_U(2, 0) STAGE_U(3, 0)
  gA += 64; gB += 64;
  asm volatile("s_waitcnt vmcnt(4)" ::: "memory");
  __builtin_amdgcn_sched_barrier(0);
  __builtin_amdgcn_s_barrier();
  __builtin_amdgcn_sched_barrier(0);

  for (int t = 0; t < NT; t += 2) {
    const bool more = (t + 2 < NT);
    // tile t in slot 0, staging tile t+1 into slot 1
    PHASE(0, 0, 0, 0, 1, 0, true, true)
    PHASE(0, 1, 0, 4, 0, 1, true, true)
    PHASE(0, 2, 1, 0, 1, 0, true, true)
    PHASE(0, 3, 1, 4, 0, 1, true, true)
    gA += 64; gB += 64;                   // -> tile t+2
    // tile t+1 in slot 1, staging tile t+2 into slot 0
    PHASE(1, 0, 0, 0, 1, 0, more, more)
    PHASE(1, 1, 0, 4, 0, 1, more, more)
    PHASE(1, 2, 1, 0, 1, 0, more, more)
    PHASE(1, 3, 1, 4, 0, 1, more, more)
    if (more) { gA += 64; gB += 64; }     // -> tile t+3
  }
#undef PHASE
#undef LDA8
#undef LDB8
#undef STAGE_U

  const int rq = q4 * 4;
  #pragma unroll
  for (int i = 0; i < 8; ++i) {
    #pragma unroll
    for (int j = 0; j < 4; ++j) {
      long col = brow0 + wc * 64 + j * 16 + fr;
      float bv = bias[col];
      #pragma unroll
      for (int r = 0; r < 4; ++r) {
        long row = arow0 + wr * 128 + i * 16 + rq + r;
        float v = acc[i][j][r] + bv;
        if (MODE == 0) {
          ((bf16_t*)outp)[row * N + col] = (bf16_t)v;
        } else if (MODE == 1) {
          ((float*)outp)[row * N + col] = v + resid[row * N + col];
        } else {
          float g = 0.5f * v * (1.0f + erff(v * 0.70710678118654752f));
          ((bf16_t*)outp)[row * N + col] = (bf16_t)g;
        }
      }
    }
  }
}

// ---------------------------------------------------------------- q softmax (in-place, per (row, head) over 64)
__global__ __launch_bounds__(256) void qsoftmax(bf16_t* __restrict__ qkv) {
  long r = blockIdx.x;
  int t = threadIdx.x, h = t >> 4, l = t & 15;
  bf16_t* p = qkv + r * 3072 + h * 64 + l * 4;
  bf16x4 v4 = *(const bf16x4*)p;
  float v0 = v4[0], v1 = v4[1], v2 = v4[2], v3 = v4[3];
  float m = fmaxf(fmaxf(v0, v1), fmaxf(v2, v3));
  #pragma unroll
  for (int o = 8; o >= 1; o >>= 1) m = fmaxf(m, __shfl_xor(m, o));
  float e0 = __expf(v0 - m), e1 = __expf(v1 - m), e2 = __expf(v2 - m), e3 = __expf(v3 - m);
  float s = e0 + e1 + e2 + e3;
  #pragma unroll
  for (int o = 8; o >= 1; o >>= 1) s += __shfl_xor(s, o);
  float inv = 1.0f / s;
  bf16x4 o4;
  o4[0] = (bf16_t)(e0 * inv); o4[1] = (bf16_t)(e1 * inv);
  o4[2] = (bf16_t)(e2 * inv); o4[3] = (bf16_t)(e3 * inv);
  *(bf16x4*)p = o4;
}

// ---------------------------------------------------------------- k column-softmax stats (online max/sum partials)
__global__ __launch_bounds__(256) void kstats_partial(const bf16_t* __restrict__ qkv,
                                                      float2* __restrict__ part) {
  int bh = blockIdx.x, ch = blockIdx.y;
  int b = bh >> 4, h = bh & 15;
  int t = threadIdx.x, d = t & 63, sr = t >> 6;
  const bf16_t* kp = qkv + (long)b * SS * 3072 + 1024 + h * 64 + d;
  float m = -INFINITY, sum = 0.f;
  for (int s = ch * 512 + sr; s < ch * 512 + 512; s += 4) {
    float v = (float)kp[(long)s * 3072];
    float nm = fmaxf(m, v);
    sum = sum * __expf(m - nm) + __expf(v - nm);
    m = nm;
  }
  __shared__ float2 red[4][64];
  red[sr][d] = make_float2(m, sum);
  __syncthreads();
  if (t < 64) {
    float2 a = red[0][t];
    #pragma unroll
    for (int i = 1; i < 4; ++i) {
      float2 p = red[i][t];
      float nm = fmaxf(a.x, p.x);
      a.y = a.y * __expf(a.x - nm) + p.y * __expf(p.x - nm);
      a.x = nm;
    }
    part[(long)(bh * 8 + ch) * 64 + t] = a;
  }
}

__global__ void kstats_merge(const float2* __restrict__ part, float2* __restrict__ stat) {
  int bh = blockIdx.x, d = threadIdx.x;  // 64 threads
  float m = -INFINITY, s = 0.f;
  #pragma unroll
  for (int c = 0; c < 8; ++c) {
    float2 p = part[(long)(bh * 8 + c) * 64 + d];
    float nm = fmaxf(m, p.x);
    s = s * __expf(m - nm) + p.y * __expf(p.x - nm);
    m = nm;
  }
  stat[bh * 64 + d] = make_float2(m, 1.0f / s);
}

// ---------------------------------------------------------------- kv = sum_s softmax_k[s,d] * v[s,e]  (partials over s-chunks)
__global__ __launch_bounds__(256) void kv_partial(const bf16_t* __restrict__ qkv,
                                                  const float2* __restrict__ stat,
                                                  float* __restrict__ kvp) {
  int bh = blockIdx.x, ch = blockIdx.y;
  int b = bh >> 4, h = bh & 15;
  int t = threadIdx.x;
  __shared__ float  Kexp[64][65];
  __shared__ bf16_t Vs[64][72];
  __shared__ float  kmaxs[64], kinvs[64];
  if (t < 64) { float2 p = stat[bh * 64 + t]; kmaxs[t] = p.x; kinvs[t] = p.y; }
  int rowl = t >> 2, c0 = (t & 3) * 16;
  int dd = t >> 2, e0 = (t & 3) * 16;
  float acc[16] = {};
  for (int sb = 0; sb < 8; ++sb) {
    long s = (long)ch * 512 + sb * 64 + rowl;
    const bf16_t* base = qkv + ((long)b * SS + s) * 3072 + h * 64;
    bf16x8 k0 = *(const bf16x8*)(base + 1024 + c0);
    bf16x8 k1 = *(const bf16x8*)(base + 1024 + c0 + 8);
    bf16x8 v0 = *(const bf16x8*)(base + 2048 + c0);
    bf16x8 v1 = *(const bf16x8*)(base + 2048 + c0 + 8);
    __syncthreads();
    #pragma unroll
    for (int j = 0; j < 8; ++j) {
      Kexp[rowl][c0 + j]     = __expf((float)k0[j] - kmaxs[c0 + j]) * kinvs[c0 + j];
      Kexp[rowl][c0 + 8 + j] = __expf((float)k1[j] - kmaxs[c0 + 8 + j]) * kinvs[c0 + 8 + j];
    }
    *(bf16x8*)&Vs[rowl][c0]     = v0;
    *(bf16x8*)&Vs[rowl][c0 + 8] = v1;
    __syncthreads();
    for (int ls = 0; ls < 64; ++ls) {
      float kd = Kexp[ls][dd];
      bf16x8 va = *(const bf16x8*)&Vs[ls][e0];
      bf16x8 vb = *(const bf16x8*)&Vs[ls][e0 + 8];
      #pragma unroll
      for (int j = 0; j < 8; ++j) {
        acc[j]     += kd * (float)va[j];
        acc[j + 8] += kd * (float)vb[j];
      }
    }
  }
  float* dst = kvp + (long)(bh * 8 + ch) * 4096 + dd * 64 + e0;
  #pragma unroll
  for (int j = 0; j < 16; ++j) dst[j] = acc[j];
}

// reduce partials, store TRANSPOSED bf16: kvT[bh][e][d]
__global__ void kv_reduce(const float* __restrict__ kvp, bf16_t* __restrict__ kvT) {
  int bh = blockIdx.x, t = threadIdx.x;
  for (int p = t; p < 4096; p += 256) {
    int d = p >> 6, e = p & 63;
    float s = 0.f;
    #pragma unroll
    for (int c = 0; c < 8; ++c) s += kvp[(long)(bh * 8 + c) * 4096 + p];
    kvT[(long)bh * 4096 + e * 64 + d] = (bf16_t)s;
  }
}

// ---------------------------------------------------------------- out[s,e] = q_sm[s,:] @ kv[:,e]  via MFMA, per (b,h)
__global__ __launch_bounds__(256) void attn_apply(const bf16_t* __restrict__ qkv,
                                                  const bf16_t* __restrict__ kvT,
                                                  bf16_t* __restrict__ attn) {
  int bh = blockIdx.x, sc = blockIdx.y;
  int b = bh >> 4, h = bh & 15;
  int t = threadIdx.x, lane = t & 63, w = t >> 6;
  __shared__ bf16_t kvs[64 * 64];
  for (int i = t * 8; i < 4096; i += 256 * 8)
    *(bf16x8*)&kvs[i] = *(const bf16x8*)(kvT + (long)bh * 4096 + i);
  __syncthreads();
  int fr = lane & 15, kq = (lane >> 4) * 8;
  long qrow = (long)b * SS + sc * 128 + w * 32;
  f32x4 acc[2][4] = {};
  #pragma unroll
  for (int kk = 0; kk < 2; ++kk) {
    bf16x8 a0 = *(const bf16x8*)(qkv + (qrow + fr) * 3072      + h * 64 + kk * 32 + kq);
    bf16x8 a1 = *(const bf16x8*)(qkv + (qrow + 16 + fr) * 3072 + h * 64 + kk * 32 + kq);
    #pragma unroll
    for (int j = 0; j < 4; ++j) {
      bf16x8 bfr = *(const bf16x8*)&kvs[(j * 16 + fr) * 64 + kk * 32 + kq];
      acc[0][j] = MFMA16(a0, bfr, acc[0][j]);
      acc[1][j] = MFMA16(a1, bfr, acc[1][j]);
    }
  }
  int rq = (lane >> 4) * 4;
  #pragma unroll
  for (int i = 0; i < 2; ++i)
    #pragma unroll
    for (int j = 0; j < 4; ++j)
      #pragma unroll
      for (int r = 0; r < 4; ++r)
        attn[(qrow + i * 16 + rq + r) * 1024 + h * 64 + j * 16 + fr] = (bf16_t)acc[i][j][r];
}

// ---------------------------------------------------------------- launch
extern "C" void kernel_launch(void* const* d_in, const int* in_sizes, int n_in,
                              void* d_out, int out_size, void* d_ws, size_t ws_size,
                              hipStream_t stream) {
  (void)in_sizes; (void)n_in; (void)out_size;
  const float* x      = (const float*)d_in[0];
  const float* w_qkv  = (const float*)d_in[1];
  const float* b_qkv  = (const float*)d_in[2];
  const float* w_out  = (const float*)d_in[3];
  const float* b_out  = (const float*)d_in[4];
  const float* w_ffn1 = (const float*)d_in[5];
  const float* b_ffn1 = (const float*)d_in[6];
  const float* w_ffn2 = (const float*)d_in[7];
  const float* b_ffn2 = (const float*)d_in[8];
  const float* g1     = (const float*)d_in[9];
  const float* be1    = (const float*)d_in[10];
  const float* g2     = (const float*)d_in[11];
  const float* be2    = (const float*)d_in[12];

  char* ws = (char*)d_ws;
  constexpr size_t WT_QKV_OFF  = 0;
  constexpr size_t WT_OUT_OFF  = WT_QKV_OFF  + 6291456;
  constexpr size_t WT_FFN1_OFF = WT_OUT_OFF  + 2097152;
  constexpr size_t WT_FFN2_OFF = WT_FFN1_OFF + 8388608;
  constexpr size_t KSTATP_OFF  = WT_FFN2_OFF + 8388608;
  constexpr size_t KSTAT_OFF   = KSTATP_OFF  + 262144;
  constexpr size_t KVP_OFF     = KSTAT_OFF   + 32768;
  constexpr size_t KVT_OFF     = KVP_OFF     + 8388608;
  constexpr size_t ACT1_OFF    = KVT_OFF     + 524288;
  constexpr size_t BIG_OFF     = ACT1_OFF    + 33554432;          // 67,928,064

  bf16_t* WT_QKV  = (bf16_t*)(ws + WT_QKV_OFF);
  bf16_t* WT_OUT  = (bf16_t*)(ws + WT_OUT_OFF);
  bf16_t* WT_FFN1 = (bf16_t*)(ws + WT_FFN1_OFF);
  bf16_t* WT_FFN2 = (bf16_t*)(ws + WT_FFN2_OFF);
  float2* KSTATP  = (float2*)(ws + KSTATP_OFF);
  float2* KSTAT   = (float2*)(ws + KSTAT_OFF);
  float*  KVP     = (float*) (ws + KVP_OFF);
  bf16_t* KVT     = (bf16_t*)(ws + KVT_OFF);
  bf16_t* ACT1    = (bf16_t*)(ws + ACT1_OFF);
  bf16_t* QKV     = (bf16_t*)(ws + BIG_OFF);   // 96 MB
  bf16_t* GACT    = (bf16_t*)(ws + BIG_OFF);   // up to 128 MB, after QKV dead
  float*  Y       = (float*)  d_out;           // residual mid-buffer lives in d_out

  const bool big_ws = ws_size >= (size_t)(BIG_OFF + 134217728ull);

  wtrans<<<dim3(3072 / 32, 1024 / 32), dim3(32, 8), 0, stream>>>(w_qkv,  WT_QKV,  1024, 3072);
  wtrans<<<dim3(1024 / 32, 1024 / 32), dim3(32, 8), 0, stream>>>(w_out,  WT_OUT,  1024, 1024);
  wtrans<<<dim3(4096 / 32, 1024 / 32), dim3(32, 8), 0, stream>>>(w_ffn1, WT_FFN1, 1024, 4096);
  wtrans<<<dim3(1024 / 32, 4096 / 32), dim3(32, 8), 0, stream>>>(w_ffn2, WT_FFN2, 4096, 1024);

  ln_kernel<<<NROWS, 256, 0, stream>>>(x, g1, be1, ACT1);

  // qkv = ln1 @ WqkvT + b
  gemm256<0><<<dim3(3072 / 256, NROWS / 256), 512, 0, stream>>>(ACT1, WT_QKV, b_qkv, nullptr, QKV, NROWS, 3072, 1024);

  qsoftmax<<<NROWS, 256, 0, stream>>>(QKV);
  kstats_partial<<<dim3(64, 8), 256, 0, stream>>>(QKV, KSTATP);
  kstats_merge<<<64, 64, 0, stream>>>(KSTATP, KSTAT);
  kv_partial<<<dim3(64, 8), 256, 0, stream>>>(QKV, KSTAT, KVP);
  kv_reduce<<<64, 256, 0, stream>>>(KVP, KVT);
  attn_apply<<<dim3(64, SS / 128), 256, 0, stream>>>(QKV, KVT, ACT1);

  // y = x + attn_cat @ WoutT + b  -> d_out  (QKV now dead)
  gemm256<1><<<dim3(1024 / 256, NROWS / 256), 512, 0, stream>>>(ACT1, WT_OUT, b_out, x, Y, NROWS, 1024, 1024);

  ln_kernel<<<NROWS, 256, 0, stream>>>(Y, g2, be2, ACT1);

  if (big_ws) {
    gemm256<2><<<dim3(4096 / 256, NROWS / 256), 512, 0, stream>>>(ACT1, WT_FFN1, b_ffn1, nullptr, GACT, NROWS, 4096, 1024);
    gemm256<1><<<dim3(1024 / 256, NROWS / 256), 512, 0, stream>>>(GACT, WT_FFN2, b_ffn2, x, (float*)d_out, NROWS, 1024, 4096);
  } else {
    for (int c = 0; c < 2; ++c) {
      const long r0 = (long)c * 8192;
      gemm256<2><<<dim3(4096 / 256, 8192 / 256), 512, 0, stream>>>(
          ACT1 + r0 * 1024, WT_FFN1, b_ffn1, nullptr, GACT, 8192, 4096, 1024);
      gemm256<1><<<dim3(1024 / 256, 8192 / 256), 512, 0, stream>>>(
          GACT, WT_FFN2, b_ffn2, x + r0 * 1024, (float*)d_out + r0 * 1024, 8192, 1024, 4096);
    }
  }
}

// Round 9
// 721.403 us; speedup vs baseline: 1.1345x; 1.0193x over previous
//
#include <hip/hip_runtime.h>
#include <hip/hip_bf16.h>
#include <cstdint>
#include <cstddef>

#define DIMC 1024
#define HEADS 16
#define HD 64
#define DFF 4096
#define BB 4
#define SS 4096
#define NROWS (BB*SS)   // 16384

typedef __bf16 bf16_t;
typedef __bf16 bf16x8 __attribute__((ext_vector_type(8)));
typedef __bf16 bf16x4 __attribute__((ext_vector_type(4)));
typedef float  f32x4  __attribute__((ext_vector_type(4)));

#define GLDS16(gp, lp) \
  __builtin_amdgcn_global_load_lds((const __attribute__((address_space(1))) void*)(gp), \
                                   (__attribute__((address_space(3))) void*)(lp), 16, 0, 0)

#define MFMA16(a, b, c) __builtin_amdgcn_mfma_f32_16x16x32_bf16((a), (b), (c), 0, 0, 0)

// ---------------------------------------------------------------- weight transpose f32[K][N] -> bf16[N][K]
__global__ __launch_bounds__(256) void wtrans(const float* __restrict__ W, bf16_t* __restrict__ Wt,
                                              int K, int N) {
  __shared__ float tile[32][33];
  int c0 = blockIdx.x * 32, r0 = blockIdx.y * 32;
  int tx = threadIdx.x, ty = threadIdx.y;
  #pragma unroll
  for (int i = 0; i < 32; i += 8)
    tile[ty + i][tx] = W[(long)(r0 + ty + i) * N + c0 + tx];
  __syncthreads();
  #pragma unroll
  for (int i = 0; i < 32; i += 8)
    Wt[(long)(c0 + ty + i) * K + r0 + tx] = (bf16_t)tile[tx][ty + i];
}

// ---------------------------------------------------------------- LayerNorm f32 row -> bf16 row
__global__ __launch_bounds__(256) void ln_kernel(const float* __restrict__ in,
                                                 const float* __restrict__ gamma,
                                                 const float* __restrict__ beta,
                                                 bf16_t* __restrict__ out) {
  long r = blockIdx.x;
  int t = threadIdx.x;
  float4 v = ((const float4*)(in + r * DIMC))[t];
  float s  = v.x + v.y + v.z + v.w;
  float sq = v.x * v.x + v.y * v.y + v.z * v.z + v.w * v.w;
  #pragma unroll
  for (int o = 32; o > 0; o >>= 1) { s += __shfl_xor(s, o); sq += __shfl_xor(sq, o); }
  __shared__ float red[8];
  if ((t & 63) == 0) { red[(t >> 6) * 2] = s; red[(t >> 6) * 2 + 1] = sq; }
  __syncthreads();
  s  = red[0] + red[2] + red[4] + red[6];
  sq = red[1] + red[3] + red[5] + red[7];
  float mu  = s * (1.0f / DIMC);
  float var = sq * (1.0f / DIMC) - mu * mu;
  float rs  = 1.0f / sqrtf(var + 1e-5f);
  float4 g  = ((const float4*)gamma)[t];
  float4 bb = ((const float4*)beta)[t];
  bf16x4 o;
  o[0] = (bf16_t)((v.x - mu) * rs * g.x + bb.x);
  o[1] = (bf16_t)((v.y - mu) * rs * g.y + bb.y);
  o[2] = (bf16_t)((v.z - mu) * rs * g.z + bb.z);
  o[3] = (bf16_t)((v.w - mu) * rs * g.w + bb.w);
  ((bf16x4*)(out + r * DIMC))[t] = o;
}

// ---------------------------------------------------------------- 256x256 GEMM, 8 waves, BK=64, 4-phase interleave,
// XCD-swizzled block mapping, 3-phase-covered staging, derived vmcnt, hoisted LDS addresses.
// LDS layout [op][slot][kh][256][32]: op stride 64KiB, slot 32KiB, kh 16KiB, row 64B.
template <int MODE>
__global__ __launch_bounds__(512, 2) void gemm256(const bf16_t* __restrict__ A,
                                                  const bf16_t* __restrict__ Bt,
                                                  const float* __restrict__ bias,
                                                  const float* __restrict__ resid,
                                                  void* __restrict__ outp,
                                                  int M, int N, int K) {
  __shared__ bf16_t lds[2][2][2][256][32];   // 128 KiB
  const int tid  = threadIdx.x;
  const int lane = tid & 63;
  const int wr   = (tid >> 6) >> 2;   // 0..1  M-half
  const int wc   = (tid >> 6) & 3;    // 0..3  N-quarter

  // T1: bijective XCD swizzle (nwg%8==0 for all launches) + 8-row x 4-col grouping
  // so each XCD's ~32 concurrent blocks share A/B panels (working set ~6MB).
  const int nwg  = gridDim.x * gridDim.y;
  const int bid0 = blockIdx.y * gridDim.x + blockIdx.x;
  const int lg   = (bid0 & 7) * (nwg >> 3) + (bid0 >> 3);
  const int span = (int)gridDim.y << 2;          // gridDim.y * 4  (gridDim.x % 4 == 0)
  const int gidx = lg / span;
  const int rem  = lg - gidx * span;
  const int by_  = rem >> 2;
  const int bx_  = (gidx << 2) + (rem & 3);
  const long arow0 = (long)by_ * 256;
  const long brow0 = (long)bx_ * 256;

  const int fr = lane & 15;
  const int q4 = lane >> 4;

  const int srow = tid >> 2;          // staging row 0..127 (then +128)
  const int sc   = tid & 3;           // staging 16B chunk within k-half
  const int gch  = sc ^ ((srow >> 1) & 3);          // lane-constant source chunk
  const int swzB = (q4 ^ ((fr >> 1) & 3)) * 16;     // lane-constant read swizzle (bytes)

  char* const ldsB  = (char*)&lds[0][0][0][0][0];
  const char* aRead = ldsB +         (wr * 128 + fr) * 64 + swzB;
  const char* bRead = ldsB + 65536 + (wc * 64  + fr) * 64 + swzB;
  char* const dstA  = ldsB + srow * 64 + sc * 16;   // linear, gload_lds-safe
  char* const dstB  = dstA + 65536;

  const long rs128 = 128 * (long)K;
  const bf16_t* gA = A  + (arow0 + srow) * (long)K + gch * 8;
  const bf16_t* gB = Bt + (brow0 + srow) * (long)K + gch * 8;

  f32x4 acc[8][4] = {};
  bf16x8 bf[4];
  const int NT = K >> 6;              // 16 or 64 here (even)

  // stage unit U (0:A-kh0 1:B-kh0 2:A-kh1 3:B-kh1) of the tile gA/gB point at, into slot DS.
#define STAGE_U(U, DS)                                                         \
  {                                                                            \
    constexpr int op_ = (U) & 1, kh_ = (U) >> 1;                               \
    const bf16_t* g_ = (op_ ? gB : gA) + kh_ * 32;                             \
    char* d_ = (op_ ? dstB : dstA) + (DS) * 32768 + kh_ * 16384;               \
    GLDS16(g_, d_);                                                            \
    GLDS16(g_ + rs128, d_ + 8192);                                             \
  }

#define LDA8(S, KS, I) (*(const bf16x8*)(aRead + (S) * 32768 + (KS) * 16384 + (I) * 1024))
#define LDB8(S, KS, J) (*(const bf16x8*)(bRead + (S) * 32768 + (KS) * 16384 + (J) * 1024))

// P0/P2 stage two units (UA,UB) of the next tile; P1/P3 carry the counted vmcnt.
// Guard chain: P1's vmcnt+barrier covers P2/P3 reads (U2,U3); P3's covers next tile's
// P0/P1 reads (U0,U1). Every unit is waited exactly 3 phases after issue.
#define PHASE(S, UA, UB, KS, I0, READB, VMF, DOSTG, VMMORE)                   \
  {                                                                           \
    if (DOSTG) { STAGE_U(UA, (S) ^ 1) STAGE_U(UB, (S) ^ 1) }                  \
    bf16x8 a0 = LDA8(S, KS, I0 + 0), a1 = LDA8(S, KS, I0 + 1),                \
           a2 = LDA8(S, KS, I0 + 2), a3 = LDA8(S, KS, I0 + 3);                \
    if (READB) {                                                              \
      bf[0] = LDB8(S, KS, 0); bf[1] = LDB8(S, KS, 1);                         \
      bf[2] = LDB8(S, KS, 2); bf[3] = LDB8(S, KS, 3);                         \
    }                                                                         \
    if (VMF) {                                                                \
      if (VMMORE) asm volatile("s_waitcnt vmcnt(4)" ::: "memory");            \
      else        asm volatile("s_waitcnt vmcnt(0)" ::: "memory");            \
    }                                                                         \
    __builtin_amdgcn_sched_barrier(0);                                        \
    __builtin_amdgcn_s_barrier();                                             \
    __builtin_amdgcn_sched_barrier(0);                                        \
    __builtin_amdgcn_s_setprio(1);                                            \
    acc[I0+0][0] = MFMA16(a0, bf[0], acc[I0+0][0]);                           \
    acc[I0+0][1] = MFMA16(a0, bf[1], acc[I0+0][1]);                           \
    acc[I0+0][2] = MFMA16(a0, bf[2], acc[I0+0][2]);                           \
    acc[I0+0][3] = MFMA16(a0, bf[3], acc[I0+0][3]);                           \
    acc[I0+1][0] = MFMA16(a1, bf[0], acc[I0+1][0]);                           \
    acc[I0+1][1] = MFMA16(a1, bf[1], acc[I0+1][1]);                           \
    acc[I0+1][2] = MFMA16(a1, bf[2], acc[I0+1][2]);                           \
    acc[I0+1][3] = MFMA16(a1, bf[3], acc[I0+1][3]);                           \
    acc[I0+2][0] = MFMA16(a2, bf[0], acc[I0+2][0]);                           \
    acc[I0+2][1] = MFMA16(a2, bf[1], acc[I0+2][1]);                           \
    acc[I0+2][2] = MFMA16(a2, bf[2], acc[I0+2][2]);                           \
    acc[I0+2][3] = MFMA16(a2, bf[3], acc[I0+2][3]);                           \
    acc[I0+3][0] = MFMA16(a3, bf[0], acc[I0+3][0]);                           \
    acc[I0+3][1] = MFMA16(a3, bf[1], acc[I0+3][1]);                           \
    acc[I0+3][2] = MFMA16(a3, bf[2], acc[I0+3][2]);                           \
    acc[I0+3][3] = MFMA16(a3, bf[3], acc[I0+3][3]);                           \
    __builtin_amdgcn_s_setprio(0);                                            \
    __builtin_amdgcn_sched_barrier(0);                                        \
    __builtin_amdgcn_s_barrier();                                             \
    __builtin_amdgcn_sched_barrier(0);                                        \
  }

  // prologue: stage tile 0 fully into slot 0; wait for U0,U1; advance to tile 1
  STAGE_U(0, 0) STAGE_U(1, 0) STAGE_U(2, 0) STAGE_U(3, 0)
  gA += 64; gB += 64;
  asm volatile("s_waitcnt vmcnt(4)" ::: "memory");
  __builtin_amdgcn_sched_barrier(0);
  __builtin_amdgcn_s_barrier();
  __builtin_amdgcn_sched_barrier(0);

  for (int t = 0; t < NT; t += 2) {
    const bool more = (t + 2 < NT);
    // tile t in slot 0, staging tile t+1 into slot 1
    PHASE(0, 0, 1, 0, 0, 1, 0, true, true)
    PHASE(0, 0, 0, 0, 4, 0, 1, false, true)
    PHASE(0, 2, 3, 1, 0, 1, 0, true, true)
    PHASE(0, 0, 0, 1, 4, 0, 1, false, true)
    gA += 64; gB += 64;                   // -> tile t+2
    // tile t+1 in slot 1, staging tile t+2 into slot 0
    PHASE(1, 0, 1, 0, 0, 1, 0, more, true)
    PHASE(1, 0, 0, 0, 4, 0, 1, false, more)
    PHASE(1, 2, 3, 1, 0, 1, 0, more, true)
    PHASE(1, 0, 0, 1, 4, 0, 1, false, more)
    if (more) { gA += 64; gB += 64; }     // -> tile t+3
  }
#undef PHASE
#undef LDA8
#undef LDB8
#undef STAGE_U

  const int rq = q4 * 4;
  #pragma unroll
  for (int i = 0; i < 8; ++i) {
    #pragma unroll
    for (int j = 0; j < 4; ++j) {
      long col = brow0 + wc * 64 + j * 16 + fr;
      float bv = bias[col];
      #pragma unroll
      for (int r = 0; r < 4; ++r) {
        long row = arow0 + wr * 128 + i * 16 + rq + r;
        float v = acc[i][j][r] + bv;
        if (MODE == 0) {
          ((bf16_t*)outp)[row * N + col] = (bf16_t)v;
        } else if (MODE == 1) {
          ((float*)outp)[row * N + col] = v + resid[row * N + col];
        } else {
          float g = 0.5f * v * (1.0f + erff(v * 0.70710678118654752f));
          ((bf16_t*)outp)[row * N + col] = (bf16_t)g;
        }
      }
    }
  }
}

// ---------------------------------------------------------------- q softmax (in-place, per (row, head) over 64)
__global__ __launch_bounds__(256) void qsoftmax(bf16_t* __restrict__ qkv) {
  long r = blockIdx.x;
  int t = threadIdx.x, h = t >> 4, l = t & 15;
  bf16_t* p = qkv + r * 3072 + h * 64 + l * 4;
  bf16x4 v4 = *(const bf16x4*)p;
  float v0 = v4[0], v1 = v4[1], v2 = v4[2], v3 = v4[3];
  float m = fmaxf(fmaxf(v0, v1), fmaxf(v2, v3));
  #pragma unroll
  for (int o = 8; o >= 1; o >>= 1) m = fmaxf(m, __shfl_xor(m, o));
  float e0 = __expf(v0 - m), e1 = __expf(v1 - m), e2 = __expf(v2 - m), e3 = __expf(v3 - m);
  float s = e0 + e1 + e2 + e3;
  #pragma unroll
  for (int o = 8; o >= 1; o >>= 1) s += __shfl_xor(s, o);
  float inv = 1.0f / s;
  bf16x4 o4;
  o4[0] = (bf16_t)(e0 * inv); o4[1] = (bf16_t)(e1 * inv);
  o4[2] = (bf16_t)(e2 * inv); o4[3] = (bf16_t)(e3 * inv);
  *(bf16x4*)p = o4;
}

// ---------------------------------------------------------------- k column-softmax stats (online max/sum partials)
__global__ __launch_bounds__(256) void kstats_partial(const bf16_t* __restrict__ qkv,
                                                      float2* __restrict__ part) {
  int bh = blockIdx.x, ch = blockIdx.y;
  int b = bh >> 4, h = bh & 15;
  int t = threadIdx.x, d = t & 63, sr = t >> 6;
  const bf16_t* kp = qkv + (long)b * SS * 3072 + 1024 + h * 64 + d;
  float m = -INFINITY, sum = 0.f;
  for (int s = ch * 512 + sr; s < ch * 512 + 512; s += 4) {
    float v = (float)kp[(long)s * 3072];
    float nm = fmaxf(m, v);
    sum = sum * __expf(m - nm) + __expf(v - nm);
    m = nm;
  }
  __shared__ float2 red[4][64];
  red[sr][d] = make_float2(m, sum);
  __syncthreads();
  if (t < 64) {
    float2 a = red[0][t];
    #pragma unroll
    for (int i = 1; i < 4; ++i) {
      float2 p = red[i][t];
      float nm = fmaxf(a.x, p.x);
      a.y = a.y * __expf(a.x - nm) + p.y * __expf(p.x - nm);
      a.x = nm;
    }
    part[(long)(bh * 8 + ch) * 64 + t] = a;
  }
}

__global__ void kstats_merge(const float2* __restrict__ part, float2* __restrict__ stat) {
  int bh = blockIdx.x, d = threadIdx.x;  // 64 threads
  float m = -INFINITY, s = 0.f;
  #pragma unroll
  for (int c = 0; c < 8; ++c) {
    float2 p = part[(long)(bh * 8 + c) * 64 + d];
    float nm = fmaxf(m, p.x);
    s = s * __expf(m - nm) + p.y * __expf(p.x - nm);
    m = nm;
  }
  stat[bh * 64 + d] = make_float2(m, 1.0f / s);
}

// ---------------------------------------------------------------- kv = sum_s softmax_k[s,d] * v[s,e]  (partials over s-chunks)
__global__ __launch_bounds__(256) void kv_partial(const bf16_t* __restrict__ qkv,
                                                  const float2* __restrict__ stat,
                                                  float* __restrict__ kvp) {
  int bh = blockIdx.x, ch = blockIdx.y;
  int b = bh >> 4, h = bh & 15;
  int t = threadIdx.x;
  __shared__ float  Kexp[64][65];
  __shared__ bf16_t Vs[64][72];
  __shared__ float  kmaxs[64], kinvs[64];
  if (t < 64) { float2 p = stat[bh * 64 + t]; kmaxs[t] = p.x; kinvs[t] = p.y; }
  int rowl = t >> 2, c0 = (t & 3) * 16;
  int dd = t >> 2, e0 = (t & 3) * 16;
  float acc[16] = {};
  for (int sb = 0; sb < 8; ++sb) {
    long s = (long)ch * 512 + sb * 64 + rowl;
    const bf16_t* base = qkv + ((long)b * SS + s) * 3072 + h * 64;
    bf16x8 k0 = *(const bf16x8*)(base + 1024 + c0);
    bf16x8 k1 = *(const bf16x8*)(base + 1024 + c0 + 8);
    bf16x8 v0 = *(const bf16x8*)(base + 2048 + c0);
    bf16x8 v1 = *(const bf16x8*)(base + 2048 + c0 + 8);
    __syncthreads();
    #pragma unroll
    for (int j = 0; j < 8; ++j) {
      Kexp[rowl][c0 + j]     = __expf((float)k0[j] - kmaxs[c0 + j]) * kinvs[c0 + j];
      Kexp[rowl][c0 + 8 + j] = __expf((float)k1[j] - kmaxs[c0 + 8 + j]) * kinvs[c0 + 8 + j];
    }
    *(bf16x8*)&Vs[rowl][c0]     = v0;
    *(bf16x8*)&Vs[rowl][c0 + 8] = v1;
    __syncthreads();
    for (int ls = 0; ls < 64; ++ls) {
      float kd = Kexp[ls][dd];
      bf16x8 va = *(const bf16x8*)&Vs[ls][e0];
      bf16x8 vb = *(const bf16x8*)&Vs[ls][e0 + 8];
      #pragma unroll
      for (int j = 0; j < 8; ++j) {
        acc[j]     += kd * (float)va[j];
        acc[j + 8] += kd * (float)vb[j];
      }
    }
  }
  float* dst = kvp + (long)(bh * 8 + ch) * 4096 + dd * 64 + e0;
  #pragma unroll
  for (int j = 0; j < 16; ++j) dst[j] = acc[j];
}

// reduce partials, store TRANSPOSED bf16: kvT[bh][e][d]
__global__ void kv_reduce(const float* __restrict__ kvp, bf16_t* __restrict__ kvT) {
  int bh = blockIdx.x, t = threadIdx.x;
  for (int p = t; p < 4096; p += 256) {
    int d = p >> 6, e = p & 63;
    float s = 0.f;
    #pragma unroll
    for (int c = 0; c < 8; ++c) s += kvp[(long)(bh * 8 + c) * 4096 + p];
    kvT[(long)bh * 4096 + e * 64 + d] = (bf16_t)s;
  }
}

// ---------------------------------------------------------------- out[s,e] = q_sm[s,:] @ kv[:,e]  via MFMA, per (b,h)
__global__ __launch_bounds__(256) void attn_apply(const bf16_t* __restrict__ qkv,
                                                  const bf16_t* __restrict__ kvT,
                                                  bf16_t* __restrict__ attn) {
  int bh = blockIdx.x, sc = blockIdx.y;
  int b = bh >> 4, h = bh & 15;
  int t = threadIdx.x, lane = t & 63, w = t >> 6;
  __shared__ bf16_t kvs[64 * 64];
  for (int i = t * 8; i < 4096; i += 256 * 8)
    *(bf16x8*)&kvs[i] = *(const bf16x8*)(kvT + (long)bh * 4096 + i);
  __syncthreads();
  int fr = lane & 15, kq = (lane >> 4) * 8;
  long qrow = (long)b * SS + sc * 128 + w * 32;
  f32x4 acc[2][4] = {};
  #pragma unroll
  for (int kk = 0; kk < 2; ++kk) {
    bf16x8 a0 = *(const bf16x8*)(qkv + (qrow + fr) * 3072      + h * 64 + kk * 32 + kq);
    bf16x8 a1 = *(const bf16x8*)(qkv + (qrow + 16 + fr) * 3072 + h * 64 + kk * 32 + kq);
    #pragma unroll
    for (int j = 0; j < 4; ++j) {
      bf16x8 bfr = *(const bf16x8*)&kvs[(j * 16 + fr) * 64 + kk * 32 + kq];
      acc[0][j] = MFMA16(a0, bfr, acc[0][j]);
      acc[1][j] = MFMA16(a1, bfr, acc[1][j]);
    }
  }
  int rq = (lane >> 4) * 4;
  #pragma unroll
  for (int i = 0; i < 2; ++i)
    #pragma unroll
    for (int j = 0; j < 4; ++j)
      #pragma unroll
      for (int r = 0; r < 4; ++r)
        attn[(qrow + i * 16 + rq + r) * 1024 + h * 64 + j * 16 + fr] = (bf16_t)acc[i][j][r];
}

// ---------------------------------------------------------------- launch
extern "C" void kernel_launch(void* const* d_in, const int* in_sizes, int n_in,
                              void* d_out, int out_size, void* d_ws, size_t ws_size,
                              hipStream_t stream) {
  (void)in_sizes; (void)n_in; (void)out_size;
  const float* x      = (const float*)d_in[0];
  const float* w_qkv  = (const float*)d_in[1];
  const float* b_qkv  = (const float*)d_in[2];
  const float* w_out  = (const float*)d_in[3];
  const float* b_out  = (const float*)d_in[4];
  const float* w_ffn1 = (const float*)d_in[5];
  const float* b_ffn1 = (const float*)d_in[6];
  const float* w_ffn2 = (const float*)d_in[7];
  const float* b_ffn2 = (const float*)d_in[8];
  const float* g1     = (const float*)d_in[9];
  const float* be1    = (const float*)d_in[10];
  const float* g2     = (const float*)d_in[11];
  const float* be2    = (const float*)d_in[12];

  char* ws = (char*)d_ws;
  constexpr size_t WT_QKV_OFF  = 0;
  constexpr size_t WT_OUT_OFF  = WT_QKV_OFF  + 6291456;
  constexpr size_t WT_FFN1_OFF = WT_OUT_OFF  + 2097152;
  constexpr size_t WT_FFN2_OFF = WT_FFN1_OFF + 8388608;
  constexpr size_t KSTATP_OFF  = WT_FFN2_OFF + 8388608;
  constexpr size_t KSTAT_OFF   = KSTATP_OFF  + 262144;
  constexpr size_t KVP_OFF     = KSTAT_OFF   + 32768;
  constexpr size_t KVT_OFF     = KVP_OFF     + 8388608;
  constexpr size_t ACT1_OFF    = KVT_OFF     + 524288;
  constexpr size_t BIG_OFF     = ACT1_OFF    + 33554432;          // 67,928,064

  bf16_t* WT_QKV  = (bf16_t*)(ws + WT_QKV_OFF);
  bf16_t* WT_OUT  = (bf16_t*)(ws + WT_OUT_OFF);
  bf16_t* WT_FFN1 = (bf16_t*)(ws + WT_FFN1_OFF);
  bf16_t* WT_FFN2 = (bf16_t*)(ws + WT_FFN2_OFF);
  float2* KSTATP  = (float2*)(ws + KSTATP_OFF);
  float2* KSTAT   = (float2*)(ws + KSTAT_OFF);
  float*  KVP     = (float*) (ws + KVP_OFF);
  bf16_t* KVT     = (bf16_t*)(ws + KVT_OFF);
  bf16_t* ACT1    = (bf16_t*)(ws + ACT1_OFF);
  bf16_t* QKV     = (bf16_t*)(ws + BIG_OFF);   // 96 MB
  bf16_t* GACT    = (bf16_t*)(ws + BIG_OFF);   // up to 128 MB, after QKV dead
  float*  Y       = (float*)  d_out;           // residual mid-buffer lives in d_out

  const bool big_ws = ws_size >= (size_t)(BIG_OFF + 134217728ull);

  wtrans<<<dim3(3072 / 32, 1024 / 32), dim3(32, 8), 0, stream>>>(w_qkv,  WT_QKV,  1024, 3072);
  wtrans<<<dim3(1024 / 32, 1024 / 32), dim3(32, 8), 0, stream>>>(w_out,  WT_OUT,  1024, 1024);
  wtrans<<<dim3(4096 / 32, 1024 / 32), dim3(32, 8), 0, stream>>>(w_ffn1, WT_FFN1, 1024, 4096);
  wtrans<<<dim3(1024 / 32, 4096 / 32), dim3(32, 8), 0, stream>>>(w_ffn2, WT_FFN2, 4096, 1024);

  ln_kernel<<<NROWS, 256, 0, stream>>>(x, g1, be1, ACT1);

  // qkv = ln1 @ WqkvT + b
  gemm256<0><<<dim3(3072 / 256, NROWS / 256), 512, 0, stream>>>(ACT1, WT_QKV, b_qkv, nullptr, QKV, NROWS, 3072, 1024);

  qsoftmax<<<NROWS, 256, 0, stream>>>(QKV);
  kstats_partial<<<dim3(64, 8), 256, 0, stream>>>(QKV, KSTATP);
  kstats_merge<<<64, 64, 0, stream>>>(KSTATP, KSTAT);
  kv_partial<<<dim3(64, 8), 256, 0, stream>>>(QKV, KSTAT, KVP);
  kv_reduce<<<64, 256, 0, stream>>>(KVP, KVT);
  attn_apply<<<dim3(64, SS / 128), 256, 0, stream>>>(QKV, KVT, ACT1);

  // y = x + attn_cat @ WoutT + b  -> d_out  (QKV now dead)
  gemm256<1><<<dim3(1024 / 256, NROWS / 256), 512, 0, stream>>>(ACT1, WT_OUT, b_out, x, Y, NROWS, 1024, 1024);

  ln_kernel<<<NROWS, 256, 0, stream>>>(Y, g2, be2, ACT1);

  if (big_ws) {
    gemm256<2><<<dim3(4096 / 256, NROWS / 256), 512, 0, stream>>>(ACT1, WT_FFN1, b_ffn1, nullptr, GACT, NROWS, 4096, 1024);
    gemm256<1><<<dim3(1024 / 256, NROWS / 256), 512, 0, stream>>>(GACT, WT_FFN2, b_ffn2, x, (float*)d_out, NROWS, 1024, 4096);
  } else {
    for (int c = 0; c < 2; ++c) {
      const long r0 = (long)c * 8192;
      gemm256<2><<<dim3(4096 / 256, 8192 / 256), 512, 0, stream>>>(
          ACT1 + r0 * 1024, WT_FFN1, b_ffn1, nullptr, GACT, 8192, 4096, 1024);
      gemm256<1><<<dim3(1024 / 256, 8192 / 256), 512, 0, stream>>>(
          GACT, WT_FFN2, b_ffn2, x + r0 * 1024, (float*)d_out + r0 * 1024, 8192, 1024, 4096);
    }
  }
}